// Round 18
// baseline (709.206 us; speedup 1.0000x reference)
//
#include <hip/hip_runtime.h>
#include <math.h>

namespace {

constexpr int kB = 512, kS = 200, kD = 256, kH = 4;
constexpr int kM = kB * kS;           // 102400 rows
constexpr float kEps = 1e-8f;

typedef short bf16x8 __attribute__((ext_vector_type(8)));   // 8 bf16 = 4 VGPR
typedef float f32x4 __attribute__((ext_vector_type(4)));

__device__ __forceinline__ float bf2f(unsigned short s) {
  return __uint_as_float(((unsigned)s) << 16);
}
__device__ __forceinline__ unsigned cvtpk(float lo, float hi) {
  unsigned r;
  asm("v_cvt_pk_bf16_f32 %0, %1, %2" : "=v"(r) : "v"(lo), "v"(hi));
  return r;
}
__device__ __forceinline__ void gload16(const void* g, void* l) {
  __builtin_amdgcn_global_load_lds(
      (const __attribute__((address_space(1))) void*)g,
      (__attribute__((address_space(3))) void*)l, 16, 0, 0);
}
__device__ __forceinline__ void vm3() { asm volatile("s_waitcnt vmcnt(3)" ::: "memory"); }
__device__ __forceinline__ void vm2() { asm volatile("s_waitcnt vmcnt(2)" ::: "memory"); }
__device__ __forceinline__ void vm0() { asm volatile("s_waitcnt vmcnt(0)" ::: "memory"); }
__device__ __forceinline__ void lk0() { asm volatile("s_waitcnt lgkmcnt(0)" ::: "memory"); }
__device__ __forceinline__ void bar() { asm volatile("s_barrier" ::: "memory"); }

// ---------------- weights f32 -> bf16; q-rows of in_w get g-folded ----------------
__global__ __launch_bounds__(256) void cvt4_kernel(
    const float* __restrict__ w0, const float* __restrict__ w1,
    const float* __restrict__ w2, const float* __restrict__ w3,
    const float* __restrict__ ln1g,
    unsigned short* __restrict__ o0, unsigned short* __restrict__ o1,
    unsigned short* __restrict__ o2, unsigned short* __restrict__ o3) {
  int blk = blockIdx.x;
  const float* src;
  unsigned short* dst;
  int base;
  bool isin = false;
  if (blk < 384)      { src = w0; dst = o0; base = blk; isin = true; }
  else if (blk < 512) { src = w1; dst = o1; base = blk - 384; }
  else if (blk < 640) { src = w2; dst = o2; base = blk - 512; }
  else                { src = w3; dst = o3; base = blk - 640; }
  int i4 = (base * 256 + threadIdx.x) * 4;
  float4 v = *reinterpret_cast<const float4*>(src + i4);
  if (isin) {
    int layer = (i4 >= 196608) ? 1 : 0;
    int rem = i4 - layer * 196608;
    int n = rem >> 8;
    int k = rem & 255;
    if (n < 256) {
      float4 g = *reinterpret_cast<const float4*>(ln1g + layer * 256 + k);
      v.x *= g.x; v.y *= g.y; v.z *= g.z; v.w *= g.w;
    }
  }
  uint2 o = {cvtpk(v.x, v.y), cvtpk(v.z, v.w)};
  *reinterpret_cast<uint2*>(dst + i4) = o;
}

// s1[n] = sum_k Wq[n][k]*g[k];  s2[n] = sum_k Wq[n][k]*b[k] + bias_q[n]
__global__ __launch_bounds__(64) void s1s2_kernel(
    const float* __restrict__ in_w, const float* __restrict__ in_b,
    const float* __restrict__ ln1g, const float* __restrict__ ln1b,
    float* __restrict__ s1o, float* __restrict__ s2o) {
  int blk = blockIdx.x;
  int layer = blk >> 8, n = blk & 255;
  int k = threadIdx.x * 4;
  float4 w = *reinterpret_cast<const float4*>(in_w + (size_t)layer * 196608 + n * 256 + k);
  float4 g = *reinterpret_cast<const float4*>(ln1g + layer * 256 + k);
  float4 b = *reinterpret_cast<const float4*>(ln1b + layer * 256 + k);
  float a = w.x * g.x + w.y * g.y + w.z * g.z + w.w * g.w;
  float c = w.x * b.x + w.y * b.y + w.z * b.z + w.w * b.w;
#pragma unroll
  for (int o = 32; o >= 1; o >>= 1) { a += __shfl_xor(a, o); c += __shfl_xor(c, o); }
  if (threadIdx.x == 0) {
    s1o[blk] = a;
    s2o[blk] = c + in_b[layer * 768 + n];
  }
}

// ---------------- embed: x + LN1 row-stats; 8 rows/block ----------------
__global__ __launch_bounds__(512) void embed_kernel(
    const float* __restrict__ item_emb, const float* __restrict__ pos_emb,
    const int* __restrict__ log_seqs, unsigned short* __restrict__ x,
    float2* __restrict__ stats) {
  int bs = blockIdx.x * 8 + (threadIdx.x >> 6);
  int s = bs % kS;
  int idx = log_seqs[bs];
  float msk = (idx != 0) ? 1.f : 0.f;
  int t = threadIdx.x & 63;
  float4 a = reinterpret_cast<const float4*>(item_emb + (size_t)idx * kD)[t];
  float4 p = reinterpret_cast<const float4*>(pos_emb + (size_t)s * kD)[t];
  float v[4];
  v[0] = (a.x * 16.f + p.x) * msk;
  v[1] = (a.y * 16.f + p.y) * msk;
  v[2] = (a.z * 16.f + p.z) * msk;
  v[3] = (a.w * 16.f + p.w) * msk;
  uint2 r = {cvtpk(v[0], v[1]), cvtpk(v[2], v[3])};
  reinterpret_cast<uint2*>(x + (size_t)bs * kD)[t] = r;
  float sm = v[0] + v[1] + v[2] + v[3];
#pragma unroll
  for (int o = 32; o >= 1; o >>= 1) sm += __shfl_xor(sm, o);
  float mean = sm * (1.f / kD);
  float d0 = v[0] - mean, d1 = v[1] - mean, d2 = v[2] - mean, d3 = v[3] - mean;
  float vs = d0 * d0 + d1 * d1 + d2 * d2 + d3 * d3;
#pragma unroll
  for (int o = 32; o >= 1; o >>= 1) vs += __shfl_xor(vs, o);
  if (t == 0) stats[bs] = {mean, rsqrtf(vs * (1.f / kD) + kEps)};
}

// ---------------- fused MFMA GEMM (qkv / out-proj), 3-buffer, 1 barrier/step ----------------
// MODE: 4 qkv (y0 q-affine via stats/s1/s2, else +bias); 5 out-proj (+bias + Qrec)
// LN:   0 none; 1 C=LN(v)
// G3:   1 -> 1D grid 2400, XCD/time co-located y-partners (N=768)
template <int MODE, int LN, int G3>
__global__ __launch_bounds__(512, 4) void gemm2(
    const unsigned short* __restrict__ A, int lda,
    const unsigned short* __restrict__ W,
    const float* __restrict__ bias,
    const unsigned short* __restrict__ R, int ldr,
    const float* __restrict__ lng, const float* __restrict__ lnb,
    const float* __restrict__ qg, const float* __restrict__ qb,
    const float2* __restrict__ statsIn,
    const float* __restrict__ s1v, const float* __restrict__ s2v,
    unsigned short* __restrict__ C, int ldc) {
  __shared__ __attribute__((aligned(16))) unsigned short SMEM[36864];  // 72KB
  __shared__ float red1[128][4];
  __shared__ float red2[128][4];
  const int tid = threadIdx.x, lane = tid & 63, wid = tid >> 6;
  int m0, n0;
  if (G3) {
    int g = blockIdx.x / 24, sub = blockIdx.x % 24;
    m0 = (g * 8 + (sub & 7)) * 128;
    n0 = (sub >> 3) * 256;
  } else {
    m0 = blockIdx.x * 128;
    n0 = 0;
  }
  const int wm = wid >> 2, wn = wid & 3;
  const int lrow = lane & 15, kgrp = lane >> 4;
  const int srow = tid >> 2;
  const int sslot = (tid & 3) ^ (srow & 3);
  const unsigned short* gA  = A + (size_t)(m0 + srow) * lda + sslot * 8;
  const unsigned short* gW0 = W + (size_t)(n0 + srow) * kD + sslot * 8;
  const unsigned short* gW1 = gW0 + (size_t)128 * kD;
  const int sa = (kgrp ^ (lrow & 3)) * 8;

#define STAGE(kk, bb)                                                   \
  do {                                                                  \
    gload16(gA + (kk) * 32, &SMEM[(bb) * 4096 + wid * 512]);            \
    gload16(gW0 + (kk) * 32, &SMEM[12288 + (bb) * 8192 + wid * 512]);   \
    gload16(gW1 + (kk) * 32, &SMEM[16384 + (bb) * 8192 + wid * 512]);   \
  } while (0)

  f32x4 acc[4][4] = {};
  STAGE(0, 0);
  STAGE(1, 1);
#pragma unroll
  for (int k = 0; k < 8; ++k) {
    if (k < 7) vm3(); else vm0();
    bar();
    const int buf = k % 3;
    bf16x8 af[4], bfr[4];
#pragma unroll
    for (int x = 0; x < 4; ++x) {
      af[x]  = *reinterpret_cast<const bf16x8*>(
          &SMEM[12288 + buf * 8192 + (wn * 64 + x * 16 + lrow) * 32 + sa]);
      bfr[x] = *reinterpret_cast<const bf16x8*>(
          &SMEM[buf * 4096 + (wm * 64 + x * 16 + lrow) * 32 + sa]);
    }
    if (k + 2 < 8) STAGE(k + 2, (k + 2) % 3);
    __builtin_amdgcn_s_setprio(1);
#pragma unroll
    for (int na = 0; na < 4; ++na)
#pragma unroll
      for (int mb = 0; mb < 4; ++mb)
        acc[na][mb] = __builtin_amdgcn_mfma_f32_16x16x32_bf16(
            af[na], bfr[mb], acc[na][mb], 0, 0, 0);
    __builtin_amdgcn_s_setprio(0);
  }
#undef STAGE
  __syncthreads();
  const bool qpath = (MODE == 4) && (n0 == 0);
  float2 st[4];
  if (MODE == 5 || (MODE == 4 && n0 == 0)) {
#pragma unroll
    for (int mb = 0; mb < 4; ++mb)
      st[mb] = statsIn[m0 + wm * 64 + mb * 16 + lrow];
  }
  // R cache: one ushort4 per fragment -> loaded ONCE (MODE 5 only)
  ushort4 rc[4][4];
  if (MODE == 5) {
#pragma unroll
    for (int na = 0; na < 4; ++na) {
      int gcol = n0 + wn * 64 + na * 16 + kgrp * 4;
#pragma unroll
      for (int mb = 0; mb < 4; ++mb) {
        int m = m0 + wm * 64 + mb * 16 + lrow;
        rc[na][mb] = *reinterpret_cast<const ushort4*>(R + (size_t)m * ldr + gcol);
      }
    }
  }

  auto computeX = [&](int na, int mb, float x[4]) {
    const int gcol = n0 + wn * 64 + na * 16 + kgrp * 4;
    const f32x4 v = acc[na][mb];
    if (MODE == 4 && qpath) {
      float4 t1 = *reinterpret_cast<const float4*>(s1v + gcol);
      float4 t2 = *reinterpret_cast<const float4*>(s2v + gcol);
      const float s1f[4] = {t1.x, t1.y, t1.z, t1.w};
      const float s2f[4] = {t2.x, t2.y, t2.z, t2.w};
#pragma unroll
      for (int r = 0; r < 4; ++r)
        x[r] = st[mb].y * (v[r] - st[mb].x * s1f[r]) + s2f[r];
      return;
    }
    float4 b4 = *reinterpret_cast<const float4*>(bias + gcol);
    const float bx[4] = {b4.x, b4.y, b4.z, b4.w};
    if (MODE == 4) {
#pragma unroll
      for (int r = 0; r < 4; ++r) x[r] = v[r] + bx[r];
    } else {  // MODE 5
      const unsigned short* rs = reinterpret_cast<const unsigned short*>(&rc[na][mb]);
      float4 t1 = *reinterpret_cast<const float4*>(qg + gcol);
      float4 t2 = *reinterpret_cast<const float4*>(qb + gcol);
      const float g4[4] = {t1.x, t1.y, t1.z, t1.w};
      const float qb4[4] = {t2.x, t2.y, t2.z, t2.w};
#pragma unroll
      for (int r = 0; r < 4; ++r) {
        float q = (bf2f(rs[r]) - st[mb].x) * st[mb].y * g4[r] + qb4[r];
        x[r] = v[r] + bx[r] + q;
      }
    }
  };

  float mean[4], inv[4];
  if (LN) {
    float sA[4] = {0.f, 0.f, 0.f, 0.f}, sB[4] = {0.f, 0.f, 0.f, 0.f};
#pragma unroll
    for (int na = 0; na < 4; ++na)
#pragma unroll
      for (int mb = 0; mb < 4; ++mb) {
        float x[4];
        computeX(na, mb, x);
#pragma unroll
        for (int r = 0; r < 4; ++r) { sA[mb] += x[r]; sB[mb] += x[r] * x[r]; }
      }
#pragma unroll
    for (int mb = 0; mb < 4; ++mb) {
      sA[mb] += __shfl_xor(sA[mb], 16); sA[mb] += __shfl_xor(sA[mb], 32);
      sB[mb] += __shfl_xor(sB[mb], 16); sB[mb] += __shfl_xor(sB[mb], 32);
    }
    if (kgrp == 0) {
#pragma unroll
      for (int mb = 0; mb < 4; ++mb) {
        int rl = wm * 64 + mb * 16 + lrow;
        red1[rl][wn] = sA[mb];
        red2[rl][wn] = sB[mb];
      }
    }
    __syncthreads();
#pragma unroll
    for (int mb = 0; mb < 4; ++mb) {
      int rl = wm * 64 + mb * 16 + lrow;
      float4 p1 = *reinterpret_cast<const float4*>(red1[rl]);
      float4 p2 = *reinterpret_cast<const float4*>(red2[rl]);
      float t1 = p1.x + p1.y + p1.z + p1.w;
      float t2 = p2.x + p2.y + p2.z + p2.w;
      float mu = t1 * (1.f / 256.f);
      float var = t2 * (1.f / 256.f) - mu * mu;
      mean[mb] = mu;
      inv[mb] = rsqrtf(fmaxf(var, 0.f) + kEps);
    }
  }

  // ---- LDS-transposed store ----
  unsigned short* eb = &SMEM[wid * 3072];
  const int rr = lane >> 2, c8 = (lane & 3) * 8;
#pragma unroll
  for (int hh = 0; hh < 2; ++hh) {
    lk0();
#pragma unroll
    for (int mbl = 0; mbl < 2; ++mbl) {
      int mb = hh * 2 + mbl;
#pragma unroll
      for (int na = 0; na < 4; ++na) {
        float x[4];
        computeX(na, mb, x);
        if (LN == 1) {
          int gcol = n0 + wn * 64 + na * 16 + kgrp * 4;
          float4 g4v = *reinterpret_cast<const float4*>(lng + gcol);
          float4 b4v = *reinterpret_cast<const float4*>(lnb + gcol);
          x[0] = (x[0] - mean[mb]) * inv[mb] * g4v.x + b4v.x;
          x[1] = (x[1] - mean[mb]) * inv[mb] * g4v.y + b4v.y;
          x[2] = (x[2] - mean[mb]) * inv[mb] * g4v.z + b4v.z;
          x[3] = (x[3] - mean[mb]) * inv[mb] * g4v.w + b4v.w;
        }
        uint2 o = {cvtpk(x[0], x[1]), cvtpk(x[2], x[3])};
        *reinterpret_cast<uint2*>(&eb[(mbl * 16 + lrow) * 72 + na * 16 + kgrp * 4]) = o;
      }
    }
    lk0();
#pragma unroll
    for (int rh = 0; rh < 2; ++rh) {
      int row = rh * 16 + rr;
      uint4 d0 = *reinterpret_cast<const uint4*>(&eb[row * 72 + c8]);
      uint4 d1 = *reinterpret_cast<const uint4*>(&eb[row * 72 + 32 + c8]);
      size_t gbase = (size_t)(m0 + wm * 64 + hh * 32 + row) * ldc + (n0 + wn * 64 + c8);
      *reinterpret_cast<uint4*>(C + gbase) = d0;
      *reinterpret_cast<uint4*>(C + gbase + 32) = d1;
    }
  }
}

// ---------------- fused FFN: h1 = relu(A@c1^T+b1) in LDS; y = h1@c2^T+b2+A, *mask ----------------
// LAST=0: y computed ONCE into registers; write y + stats out.
// LAST=1: fused last-LN + logits (single pass, no C write).
template <int LAST>
__global__ __launch_bounds__(512, 4) void ffn_fused(
    const unsigned short* __restrict__ A, int lda,   // ln2out
    const unsigned short* __restrict__ W1, const float* __restrict__ b1,
    const unsigned short* __restrict__ W2, const float* __restrict__ b2,
    const int* __restrict__ logseq,
    const float* __restrict__ lng, const float* __restrict__ lnb,
    float2* __restrict__ statsOut,
    const float* __restrict__ iembf, const int* __restrict__ posq,
    const int* __restrict__ negq, float* __restrict__ outlg,
    unsigned short* __restrict__ C, int ldc) {
  // SMEM: As [2][2048] @0 | Ws [2][8192] @4096 | H1 [64][256] @20480  = 72KB
  __shared__ __attribute__((aligned(16))) unsigned short SMEM[36864];
  __shared__ float red1[64][4];
  __shared__ float red2[64][4];
  const int tid = threadIdx.x, lane = tid & 63, wid = tid >> 6;
  const int m0 = blockIdx.x * 64;
  const int wm = wid >> 2, wn = wid & 3;
  const int lrow = lane & 15, kgrp = lane >> 4;
  unsigned short* As = SMEM;
  unsigned short* Ws = SMEM + 4096;
  unsigned short* H1 = SMEM + 20480;
  const int arow = (wid & 3) * 16 + (lane >> 2);
  const int aslot = (lane & 3) ^ (arow & 3);
  const unsigned short* gA = A + (size_t)(m0 + arow) * lda + aslot * 8;
  const int wrow0 = wid * 32 + (lane >> 2);
  const int wrow1 = wrow0 + 16;
  const int ws0 = (lane & 3) ^ (wrow0 & 3);
  const int ws1 = (lane & 3) ^ (wrow1 & 3);
  const unsigned short* gW10 = W1 + wrow0 * 256 + ws0 * 8;
  const unsigned short* gW11 = W1 + wrow1 * 256 + ws1 * 8;
  const unsigned short* gW20 = W2 + wrow0 * 256 + ws0 * 8;
  const unsigned short* gW21 = W2 + wrow1 * 256 + ws1 * 8;
  const int sa = (kgrp ^ (lrow & 3)) * 8;
  const f32x4 zero = {0.f, 0.f, 0.f, 0.f};

#define STG1(kk, bb)                                               \
  do {                                                             \
    if (wid < 4) gload16(gA + (kk) * 32, &As[(bb) * 2048 + wid * 512]); \
    gload16(gW10 + (kk) * 32, &Ws[(bb) * 8192 + wid * 1024]);      \
    gload16(gW11 + (kk) * 32, &Ws[(bb) * 8192 + wid * 1024 + 512]);\
  } while (0)

  f32x4 acc[4][2] = {};
  STG1(0, 0);
  STG1(1, 1);
#pragma unroll
  for (int k = 0; k < 8; ++k) {
    if (k < 7) { if (wid < 4) vm3(); else vm2(); } else vm0();
    bar();
    const int buf = k & 1;
    bf16x8 af[4], bfr[2];
#pragma unroll
    for (int x = 0; x < 4; ++x)
      af[x] = *reinterpret_cast<const bf16x8*>(
          &Ws[buf * 8192 + (wn * 64 + x * 16 + lrow) * 32 + sa]);
#pragma unroll
    for (int mb = 0; mb < 2; ++mb)
      bfr[mb] = *reinterpret_cast<const bf16x8*>(
          &As[buf * 2048 + (wm * 32 + mb * 16 + lrow) * 32 + sa]);
    __builtin_amdgcn_s_setprio(1);
#pragma unroll
    for (int na = 0; na < 4; ++na)
#pragma unroll
      for (int mb = 0; mb < 2; ++mb)
        acc[na][mb] = __builtin_amdgcn_mfma_f32_16x16x32_bf16(
            af[na], bfr[mb], acc[na][mb], 0, 0, 0);
    __builtin_amdgcn_s_setprio(0);
    bar();
    if (k + 2 < 8) STG1(k + 2, k & 1);
  }
#undef STG1
  // h1 = relu(acc + b1) -> H1 (16B-slot XOR swizzle by row&7)
#pragma unroll
  for (int na = 0; na < 4; ++na) {
    int c0 = wn * 64 + na * 16 + kgrp * 4;
    float4 b4 = *reinterpret_cast<const float4*>(b1 + c0);
#pragma unroll
    for (int mb = 0; mb < 2; ++mb) {
      int row = wm * 32 + mb * 16 + lrow;
      f32x4 v = acc[na][mb];
      float x0 = fmaxf(v[0] + b4.x, 0.f), x1 = fmaxf(v[1] + b4.y, 0.f);
      float x2 = fmaxf(v[2] + b4.z, 0.f), x3 = fmaxf(v[3] + b4.w, 0.f);
      int s = wn * 8 + na * 2 + (kgrp >> 1);
      int addr = row * 256 + ((s ^ (row & 7)) << 3) + (kgrp & 1) * 4;
      uint2 o = {cvtpk(x0, x1), cvtpk(x2, x3)};
      *reinterpret_cast<uint2*>(&H1[addr]) = o;
    }
  }
  __syncthreads();
  // ---- phase 2: y = h1 @ c2^T ----
#pragma unroll
  for (int na = 0; na < 4; ++na)
#pragma unroll
    for (int mb = 0; mb < 2; ++mb) acc[na][mb] = zero;

#define STG2(kk, bb)                                               \
  do {                                                             \
    gload16(gW20 + (kk) * 32, &Ws[(bb) * 8192 + wid * 1024]);      \
    gload16(gW21 + (kk) * 32, &Ws[(bb) * 8192 + wid * 1024 + 512]);\
  } while (0)

  STG2(0, 0);
  STG2(1, 1);
#pragma unroll
  for (int k = 0; k < 8; ++k) {
    if (k < 7) vm2(); else vm0();
    bar();
    const int buf = k & 1;
    bf16x8 af[4], bfr[2];
#pragma unroll
    for (int x = 0; x < 4; ++x)
      af[x] = *reinterpret_cast<const bf16x8*>(
          &Ws[buf * 8192 + (wn * 64 + x * 16 + lrow) * 32 + sa]);
#pragma unroll
    for (int mb = 0; mb < 2; ++mb) {
      int row = wm * 32 + mb * 16 + lrow;
      bfr[mb] = *reinterpret_cast<const bf16x8*>(
          &H1[row * 256 + (((k * 4 + kgrp) ^ (row & 7)) << 3)]);
    }
    __builtin_amdgcn_s_setprio(1);
#pragma unroll
    for (int na = 0; na < 4; ++na)
#pragma unroll
      for (int mb = 0; mb < 2; ++mb)
        acc[na][mb] = __builtin_amdgcn_mfma_f32_16x16x32_bf16(
            af[na], bfr[mb], acc[na][mb], 0, 0, 0);
    __builtin_amdgcn_s_setprio(0);
    bar();
    if (k + 2 < 8) STG2(k + 2, k & 1);
  }
#undef STG2
  __syncthreads();  // staging dead -> reuse for SL/eb

  float msk[2];
#pragma unroll
  for (int mb = 0; mb < 2; ++mb)
    msk[mb] = (logseq[m0 + wm * 32 + mb * 16 + lrow] != 0) ? 1.f : 0.f;

  auto computeY = [&](int na, int mb, float x[4]) {
    int gcol = wn * 64 + na * 16 + kgrp * 4;
    int m = m0 + wm * 32 + mb * 16 + lrow;
    f32x4 v = acc[na][mb];
    float4 b4 = *reinterpret_cast<const float4*>(b2 + gcol);
    ushort4 rv = *reinterpret_cast<const ushort4*>(A + (size_t)m * lda + gcol);
    const unsigned short* rs = reinterpret_cast<const unsigned short*>(&rv);
    const float bx[4] = {b4.x, b4.y, b4.z, b4.w};
#pragma unroll
    for (int r = 0; r < 4; ++r)
      x[r] = (v[r] + bx[r] + bf2f(rs[r])) * msk[mb];
  };

  if (LAST == 0) {
    // y computed ONCE into registers (acc dead after)
    f32x4 yv[4][2];
#pragma unroll
    for (int na = 0; na < 4; ++na)
#pragma unroll
      for (int mb = 0; mb < 2; ++mb) {
        float x[4];
        computeY(na, mb, x);
        yv[na][mb][0] = x[0]; yv[na][mb][1] = x[1];
        yv[na][mb][2] = x[2]; yv[na][mb][3] = x[3];
      }
    float sA[2] = {0.f, 0.f}, sB[2] = {0.f, 0.f};
#pragma unroll
    for (int na = 0; na < 4; ++na)
#pragma unroll
      for (int mb = 0; mb < 2; ++mb)
#pragma unroll
        for (int r = 0; r < 4; ++r) {
          float x = yv[na][mb][r];
          sA[mb] += x;
          sB[mb] += x * x;
        }
#pragma unroll
    for (int mb = 0; mb < 2; ++mb) {
      sA[mb] += __shfl_xor(sA[mb], 16); sA[mb] += __shfl_xor(sA[mb], 32);
      sB[mb] += __shfl_xor(sB[mb], 16); sB[mb] += __shfl_xor(sB[mb], 32);
    }
    if (kgrp == 0) {
#pragma unroll
      for (int mb = 0; mb < 2; ++mb) {
        int rl = wm * 32 + mb * 16 + lrow;
        red1[rl][wn] = sA[mb];
        red2[rl][wn] = sB[mb];
      }
    }
    __syncthreads();
    if (wn == 0 && kgrp == 0) {
#pragma unroll
      for (int mb = 0; mb < 2; ++mb) {
        int rl = wm * 32 + mb * 16 + lrow;
        float4 p1 = *reinterpret_cast<const float4*>(red1[rl]);
        float4 p2 = *reinterpret_cast<const float4*>(red2[rl]);
        float t1 = p1.x + p1.y + p1.z + p1.w;
        float t2 = p2.x + p2.y + p2.z + p2.w;
        float mu = t1 * (1.f / 256.f);
        float var = t2 * (1.f / 256.f) - mu * mu;
        statsOut[m0 + rl] = {mu, rsqrtf(fmaxf(var, 0.f) + kEps)};
      }
    }
    unsigned short* eb = &SMEM[wid * 2560];
#pragma unroll
    for (int mb = 0; mb < 2; ++mb)
#pragma unroll
      for (int na = 0; na < 4; ++na) {
        uint2 o = {cvtpk(yv[na][mb][0], yv[na][mb][1]),
                   cvtpk(yv[na][mb][2], yv[na][mb][3])};
        *reinterpret_cast<uint2*>(&eb[(mb * 16 + lrow) * 72 + na * 16 + kgrp * 4]) = o;
      }
    lk0();
#pragma unroll
    for (int rh = 0; rh < 4; ++rh) {
      int row = rh * 8 + (lane >> 3);
      uint4 d = *reinterpret_cast<const uint4*>(&eb[row * 72 + (lane & 7) * 8]);
      *reinterpret_cast<uint4*>(
          C + (size_t)(m0 + wm * 32 + row) * ldc + wn * 64 + (lane & 7) * 8) = d;
    }
    return;
  }

  // ---- LAST=1: fused last-LN + logits (single pass) ----
  float* SL = reinterpret_cast<float*>(SMEM);  // [64][33]
  int pi[2], ni[2];
#pragma unroll
  for (int mb = 0; mb < 2; ++mb) {
    int m = m0 + wm * 32 + mb * 16 + lrow;
    pi[mb] = posq[m];
    ni[mb] = negq[m];
  }
#pragma unroll
  for (int mb = 0; mb < 2; ++mb) {
    float4 peL[4], neL[4];
#pragma unroll
    for (int na = 0; na < 4; ++na) {
      int gcol = wn * 64 + na * 16 + kgrp * 4;
      peL[na] = *reinterpret_cast<const float4*>(iembf + (size_t)pi[mb] * 256 + gcol);
      neL[na] = *reinterpret_cast<const float4*>(iembf + (size_t)ni[mb] * 256 + gcol);
    }
    float sa_ = 0.f, sb_ = 0.f;
    float s1p = 0.f, s2p = 0.f, s3p = 0.f;
    float s1n = 0.f, s2n = 0.f, s3n = 0.f;
#pragma unroll
    for (int na = 0; na < 4; ++na) {
      float x[4];
      computeY(na, mb, x);
      int gcol = wn * 64 + na * 16 + kgrp * 4;
      float4 g4v = *reinterpret_cast<const float4*>(lng + gcol);
      float4 b4v = *reinterpret_cast<const float4*>(lnb + gcol);
      const float gg[4] = {g4v.x, g4v.y, g4v.z, g4v.w};
      const float lb[4] = {b4v.x, b4v.y, b4v.z, b4v.w};
      const float pef[4] = {peL[na].x, peL[na].y, peL[na].z, peL[na].w};
      const float nef[4] = {neL[na].x, neL[na].y, neL[na].z, neL[na].w};
#pragma unroll
      for (int r = 0; r < 4; ++r) {
        sa_ += x[r];
        sb_ += x[r] * x[r];
        float gp = gg[r] * pef[r], gn = gg[r] * nef[r];
        s1p += x[r] * gp; s2p += gp; s3p += lb[r] * pef[r];
        s1n += x[r] * gn; s2n += gn; s3n += lb[r] * nef[r];
      }
    }
    float vals[8] = {sa_, sb_, s1p, s2p, s3p, s1n, s2n, s3n};
#pragma unroll
    for (int j = 0; j < 8; ++j) {
      vals[j] += __shfl_xor(vals[j], 16);
      vals[j] += __shfl_xor(vals[j], 32);
    }
    if (kgrp == 0) {
      int rl = wm * 32 + mb * 16 + lrow;
      float* dst = &SL[rl * 33 + wn * 8];
#pragma unroll
      for (int j = 0; j < 8; ++j) dst[j] = vals[j];
    }
  }
  __syncthreads();
  if (tid < 64) {
    float t[8] = {0.f, 0.f, 0.f, 0.f, 0.f, 0.f, 0.f, 0.f};
#pragma unroll
    for (int w = 0; w < 4; ++w) {
      const float* src = &SL[tid * 33 + w * 8];
#pragma unroll
      for (int j = 0; j < 8; ++j) t[j] += src[j];
    }
    float mean = t[0] * (1.f / 256.f);
    float var = t[1] * (1.f / 256.f) - mean * mean;
    float inv = rsqrtf(fmaxf(var, 0.f) + kEps);
    int m = m0 + tid;
    outlg[m] = inv * (t[2] - mean * t[3]) + t[4];
    outlg[(size_t)kM + m] = inv * (t[5] - mean * t[6]) + t[7];
  }
}

// ---------------- MFMA flash attention: 8 waves, fixed-max softmax ----------------
__global__ __launch_bounds__(512) void attn_mfma(unsigned short* __restrict__ qkv) {
  constexpr int kVS = 232, kQS = 768;
  __shared__ __attribute__((aligned(16))) unsigned short Kl[200 * 64];
  __shared__ __attribute__((aligned(16))) unsigned short Vt[64 * kVS];
  __shared__ __attribute__((aligned(16))) unsigned short Pt[8 * 636];
  int b = blockIdx.x >> 2, h = blockIdx.x & 3;
  int tid = threadIdx.x, lane = tid & 63, wid = tid >> 6;
  const unsigned short* kvb = qkv + (size_t)b * kS * kQS + 256 + h * 64;
  for (int i = tid; i < 1600; i += 512) {
    int row = i >> 3, slot = i & 7;
    *reinterpret_cast<uint4*>(&Kl[row * 64 + ((slot ^ (row & 7)) << 3)]) =
        *reinterpret_cast<const uint4*>(kvb + (size_t)row * kQS + slot * 8);
  }
  for (int i = tid; i < 3200; i += 512) {
    int row = i >> 4, d0 = (i & 15) * 4;
    ushort4 v = *reinterpret_cast<const ushort4*>(kvb + 256 + (size_t)row * kQS + d0);
    Vt[(d0 + 0) * kVS + row] = v.x;
    Vt[(d0 + 1) * kVS + row] = v.y;
    Vt[(d0 + 2) * kVS + row] = v.z;
    Vt[(d0 + 3) * kVS + row] = v.w;
  }
  for (int i = tid; i < 2048; i += 512) {
    int d = i >> 5, c = i & 31;
    Vt[d * kVS + 200 + c] = 0;
  }
  __syncthreads();

  int qcol = lane & 15, kgrp = lane >> 4;
  const float scale2 = 0.18033688f;  // (1/8) * log2(e)
  int packed = (wid < 3) ? (0xFFFC - wid) : (0xFF09 + (wid - 3) * 15);
  unsigned short* ptw = &Pt[wid * 636];
#pragma unroll
  for (int ti = 0; ti < 2; ++ti) {
    int t = (packed >> (ti * 4)) & 15;
    if (t == 15) break;
    int qb = t * 16;
    int qrow = qb + qcol;
    int qm = min(qrow, kS - 1);
    const unsigned short* qrp = qkv + (size_t)(b * kS + qm) * kQS + h * 64;
    bf16x8 qf0 = *reinterpret_cast<const bf16x8*>(qrp + kgrp * 8);
    bf16x8 qf1 = *reinterpret_cast<const bf16x8*>(qrp + 32 + kgrp * 8);
    f32x4 accO[4] = {};
    float l_run = 0.f;
    int nc = (qb + 47) >> 5;
    for (int c = 0; c < nc; ++c) {
      int kbase = c * 32;
      f32x4 s0 = {}, s1 = {};
      int kr0 = min(kbase + qcol, kS - 1);
      int kr1 = min(kbase + 16 + qcol, kS - 1);
      const unsigned short* K0a = &Kl[kr0 * 64 + ((kgrp ^ (kr0 & 7)) << 3)];
      const unsigned short* K0b = &Kl[kr0 * 64 + (((kgrp + 4) ^ (kr0 & 7)) << 3)];
      const unsigned short* K1a = &Kl[kr1 * 64 + ((kgrp ^ (kr1 & 7)) << 3)];
      const unsigned short* K1b = &Kl[kr1 * 64 + (((kgrp + 4) ^ (kr1 & 7)) << 3)];
      s0 = __builtin_amdgcn_mfma_f32_16x16x32_bf16(*reinterpret_cast<const bf16x8*>(K0a), qf0, s0, 0, 0, 0);
      s0 = __builtin_amdgcn_mfma_f32_16x16x32_bf16(*reinterpret_cast<const bf16x8*>(K0b), qf1, s0, 0, 0, 0);
      s1 = __builtin_amdgcn_mfma_f32_16x16x32_bf16(*reinterpret_cast<const bf16x8*>(K1a), qf0, s1, 0, 0, 0);
      s1 = __builtin_amdgcn_mfma_f32_16x16x32_bf16(*reinterpret_cast<const bf16x8*>(K1b), qf1, s1, 0, 0, 0);
      float p[8];
      float psum = 0.f;
#pragma unroll
      for (int r = 0; r < 4; ++r) {
        int key0 = kbase + kgrp * 4 + r;
        int key1 = key0 + 16;
        float x0 = (key0 <= qm) ? fmaf(s0[r], scale2, -8.f) : -3.0e38f;
        float x1 = (key1 <= qm) ? fmaf(s1[r], scale2, -8.f) : -3.0e38f;
        p[r] = exp2f(x0);
        p[r + 4] = exp2f(x1);
        psum += p[r] + p[r + 4];
      }
      l_run += psum;
      uint2 w0 = {cvtpk(p[0], p[1]), cvtpk(p[2], p[3])};
      uint2 w1 = {cvtpk(p[4], p[5]), cvtpk(p[6], p[7])};
      *reinterpret_cast<uint2*>(&ptw[qcol * 40 + kgrp * 4]) = w0;
      *reinterpret_cast<uint2*>(&ptw[qcol * 40 + 16 + kgrp * 4]) = w1;
      bf16x8 pf = *reinterpret_cast<const bf16x8*>(&ptw[qcol * 40 + kgrp * 8]);
#pragma unroll
      for (int nf = 0; nf < 4; ++nf) {
        bf16x8 vf = *reinterpret_cast<const bf16x8*>(
            &Vt[(nf * 16 + qcol) * kVS + kbase + kgrp * 8]);
        accO[nf] = __builtin_amdgcn_mfma_f32_16x16x32_bf16(vf, pf, accO[nf], 0, 0, 0);
      }
    }
    float l_tot = l_run;
    l_tot += __shfl_xor(l_tot, 16);
    l_tot += __shfl_xor(l_tot, 32);
    float inv = 1.f / l_tot;
    if (qrow < kS) {
      unsigned short* op = qkv + (size_t)(b * kS + qrow) * kQS + h * 64;
#pragma unroll
      for (int nf = 0; nf < 4; ++nf) {
        uint2 o4 = {cvtpk(accO[nf][0] * inv, accO[nf][1] * inv),
                    cvtpk(accO[nf][2] * inv, accO[nf][3] * inv)};
        *reinterpret_cast<uint2*>(op + nf * 16 + kgrp * 4) = o4;
      }
    }
  }
}

}  // namespace

extern "C" void kernel_launch(void* const* d_in, const int* in_sizes, int n_in,
                              void* d_out, int out_size, void* d_ws,
                              size_t ws_size, hipStream_t stream) {
  const float* item_emb = (const float*)d_in[0];
  const float* pos_emb  = (const float*)d_in[1];
  const float* ln1_g = (const float*)d_in[2];
  const float* ln1_b = (const float*)d_in[3];
  const float* in_w  = (const float*)d_in[4];   // [2,768,256]
  const float* in_b  = (const float*)d_in[5];   // [2,768]
  const float* out_w = (const float*)d_in[6];   // [2,256,256]
  const float* out_b = (const float*)d_in[7];
  const float* ln2_g = (const float*)d_in[8];
  const float* ln2_b = (const float*)d_in[9];
  const float* c1_w  = (const float*)d_in[10];
  const float* c1_b  = (const float*)d_in[11];
  const float* c2_w  = (const float*)d_in[12];
  const float* c2_b  = (const float*)d_in[13];
  const float* last_g = (const float*)d_in[14];
  const float* last_b = (const float*)d_in[15];
  const int* log_seqs = (const int*)d_in[17];
  const int* pos_seqs = (const int*)d_in[18];
  const int* neg_seqs = (const int*)d_in[19];
  float* out = (float*)d_out;

  size_t unit = (size_t)kM * kD;
  unsigned short* X   = (unsigned short*)d_ws;          // [M,256]
  unsigned short* QKV = X + unit;                       // [M,768]
  unsigned short* inw_bf  = X + 4 * unit;
  unsigned short* outw_bf = inw_bf + 2 * 768 * 256;
  unsigned short* c1w_bf  = outw_bf + 2 * 256 * 256;
  unsigned short* c2w_bf  = c1w_bf + 2 * 256 * 256;
  float2* stats = (float2*)(c2w_bf + 2 * 256 * 256);    // [2][M]
  float* s1buf = (float*)(stats + 2 * kM);              // [2][256]
  float* s2buf = s1buf + 512;

  cvt4_kernel<<<768, 256, 0, stream>>>(in_w, out_w, c1_w, c2_w, ln1_g,
                                       inw_bf, outw_bf, c1w_bf, c2w_bf);
  s1s2_kernel<<<512, 64, 0, stream>>>(in_w, in_b, ln1_g, ln1_b, s1buf, s2buf);
  embed_kernel<<<kM / 8, 512, 0, stream>>>(item_emb, pos_emb, log_seqs, X, stats);

  dim3 g1(kM / 128, 1);
  for (int l = 0; l < 2; ++l) {
    const unsigned short* iw = inw_bf + (size_t)l * 768 * 256;
    float2* stl = stats + (size_t)l * kM;
    // qkv = [q-affine(x) | x@Wk^T+bk | x@Wv^T+bv]
    gemm2<4, 0, 1><<<kM / 128 * 3, 512, 0, stream>>>(
        X, 256, iw, in_b + l * 768, nullptr, 0,
        nullptr, nullptr, nullptr, nullptr, stl,
        s1buf + l * 256, s2buf + l * 256, QKV, 768);
    attn_mfma<<<kB * kH, 512, 0, stream>>>(QKV);
    // ln2out = LN2(Qrec(x) + o@out_w^T + out_b)  -> QKV cols 256..511
    gemm2<5, 1, 0><<<g1, 512, 0, stream>>>(
        QKV, 768, outw_bf + (size_t)l * kD * kD, out_b + l * kD, X, 256,
        ln2_g + l * kD, ln2_b + l * kD, ln1_g + l * kD, ln1_b + l * kD,
        stl, nullptr, nullptr, QKV + 256, 768);
    if (l == 0) {
      ffn_fused<0><<<kM / 64, 512, 0, stream>>>(
          QKV + 256, 768, c1w_bf, c1_b, c2w_bf, c2_b, log_seqs,
          nullptr, nullptr, stats + kM, nullptr, nullptr, nullptr, nullptr,
          X, 256);
    } else {
      ffn_fused<1><<<kM / 64, 512, 0, stream>>>(
          QKV + 256, 768, c1w_bf + 65536, c1_b + 256, c2w_bf + 65536, c2_b + 256,
          log_seqs, last_g, last_b, nullptr, item_emb, pos_seqs, neg_seqs, out,
          nullptr, 0);
    }
  }
}

// Round 19
// 601.315 us; speedup vs baseline: 1.1794x; 1.1794x over previous
//
#include <hip/hip_runtime.h>
#include <math.h>

namespace {

constexpr int kB = 512, kS = 200, kD = 256, kH = 4;
constexpr int kM = kB * kS;           // 102400 rows
constexpr float kEps = 1e-8f;

typedef short bf16x8 __attribute__((ext_vector_type(8)));   // 8 bf16 = 4 VGPR
typedef float f32x4 __attribute__((ext_vector_type(4)));

__device__ __forceinline__ float bf2f(unsigned short s) {
  return __uint_as_float(((unsigned)s) << 16);
}
__device__ __forceinline__ unsigned cvtpk(float lo, float hi) {
  unsigned r;
  asm("v_cvt_pk_bf16_f32 %0, %1, %2" : "=v"(r) : "v"(lo), "v"(hi));
  return r;
}
__device__ __forceinline__ void gload16(const void* g, void* l) {
  __builtin_amdgcn_global_load_lds(
      (const __attribute__((address_space(1))) void*)g,
      (__attribute__((address_space(3))) void*)l, 16, 0, 0);
}
__device__ __forceinline__ void vm3() { asm volatile("s_waitcnt vmcnt(3)" ::: "memory"); }
__device__ __forceinline__ void vm2() { asm volatile("s_waitcnt vmcnt(2)" ::: "memory"); }
__device__ __forceinline__ void vm0() { asm volatile("s_waitcnt vmcnt(0)" ::: "memory"); }
__device__ __forceinline__ void lk0() { asm volatile("s_waitcnt lgkmcnt(0)" ::: "memory"); }
__device__ __forceinline__ void bar() { asm volatile("s_barrier" ::: "memory"); }

// ---------------- weights f32 -> bf16; q-rows of in_w get g-folded ----------------
__global__ __launch_bounds__(256) void cvt4_kernel(
    const float* __restrict__ w0, const float* __restrict__ w1,
    const float* __restrict__ w2, const float* __restrict__ w3,
    const float* __restrict__ ln1g,
    unsigned short* __restrict__ o0, unsigned short* __restrict__ o1,
    unsigned short* __restrict__ o2, unsigned short* __restrict__ o3) {
  int blk = blockIdx.x;
  const float* src;
  unsigned short* dst;
  int base;
  bool isin = false;
  if (blk < 384)      { src = w0; dst = o0; base = blk; isin = true; }
  else if (blk < 512) { src = w1; dst = o1; base = blk - 384; }
  else if (blk < 640) { src = w2; dst = o2; base = blk - 512; }
  else                { src = w3; dst = o3; base = blk - 640; }
  int i4 = (base * 256 + threadIdx.x) * 4;
  float4 v = *reinterpret_cast<const float4*>(src + i4);
  if (isin) {
    int layer = (i4 >= 196608) ? 1 : 0;
    int rem = i4 - layer * 196608;
    int n = rem >> 8;
    int k = rem & 255;
    if (n < 256) {
      float4 g = *reinterpret_cast<const float4*>(ln1g + layer * 256 + k);
      v.x *= g.x; v.y *= g.y; v.z *= g.z; v.w *= g.w;
    }
  }
  uint2 o = {cvtpk(v.x, v.y), cvtpk(v.z, v.w)};
  *reinterpret_cast<uint2*>(dst + i4) = o;
}

// s1[n] = sum_k Wq[n][k]*g[k];  s2[n] = sum_k Wq[n][k]*b[k] + bias_q[n]
__global__ __launch_bounds__(64) void s1s2_kernel(
    const float* __restrict__ in_w, const float* __restrict__ in_b,
    const float* __restrict__ ln1g, const float* __restrict__ ln1b,
    float* __restrict__ s1o, float* __restrict__ s2o) {
  int blk = blockIdx.x;
  int layer = blk >> 8, n = blk & 255;
  int k = threadIdx.x * 4;
  float4 w = *reinterpret_cast<const float4*>(in_w + (size_t)layer * 196608 + n * 256 + k);
  float4 g = *reinterpret_cast<const float4*>(ln1g + layer * 256 + k);
  float4 b = *reinterpret_cast<const float4*>(ln1b + layer * 256 + k);
  float a = w.x * g.x + w.y * g.y + w.z * g.z + w.w * g.w;
  float c = w.x * b.x + w.y * b.y + w.z * b.z + w.w * b.w;
#pragma unroll
  for (int o = 32; o >= 1; o >>= 1) { a += __shfl_xor(a, o); c += __shfl_xor(c, o); }
  if (threadIdx.x == 0) {
    s1o[blk] = a;
    s2o[blk] = c + in_b[layer * 768 + n];
  }
}

// ---------------- embed: x + LN1 row-stats; 8 rows/block ----------------
__global__ __launch_bounds__(512) void embed_kernel(
    const float* __restrict__ item_emb, const float* __restrict__ pos_emb,
    const int* __restrict__ log_seqs, unsigned short* __restrict__ x,
    float2* __restrict__ stats) {
  int bs = blockIdx.x * 8 + (threadIdx.x >> 6);
  int s = bs % kS;
  int idx = log_seqs[bs];
  float msk = (idx != 0) ? 1.f : 0.f;
  int t = threadIdx.x & 63;
  float4 a = reinterpret_cast<const float4*>(item_emb + (size_t)idx * kD)[t];
  float4 p = reinterpret_cast<const float4*>(pos_emb + (size_t)s * kD)[t];
  float v[4];
  v[0] = (a.x * 16.f + p.x) * msk;
  v[1] = (a.y * 16.f + p.y) * msk;
  v[2] = (a.z * 16.f + p.z) * msk;
  v[3] = (a.w * 16.f + p.w) * msk;
  uint2 r = {cvtpk(v[0], v[1]), cvtpk(v[2], v[3])};
  reinterpret_cast<uint2*>(x + (size_t)bs * kD)[t] = r;
  float sm = v[0] + v[1] + v[2] + v[3];
#pragma unroll
  for (int o = 32; o >= 1; o >>= 1) sm += __shfl_xor(sm, o);
  float mean = sm * (1.f / kD);
  float d0 = v[0] - mean, d1 = v[1] - mean, d2 = v[2] - mean, d3 = v[3] - mean;
  float vs = d0 * d0 + d1 * d1 + d2 * d2 + d3 * d3;
#pragma unroll
  for (int o = 32; o >= 1; o >>= 1) vs += __shfl_xor(vs, o);
  if (t == 0) stats[bs] = {mean, rsqrtf(vs * (1.f / kD) + kEps)};
}

// ---------------- fused MFMA GEMM (qkv / out-proj), 3-buffer, 1 barrier/step ----------------
// MODE: 4 qkv (y0 q-affine via stats/s1/s2, else +bias); 5 out-proj (+bias + Qrec)
// LN:   0 none; 1 C=LN(v)
// G3:   1 -> 1D grid 2400, XCD/time co-located y-partners (N=768)
template <int MODE, int LN, int G3>
__global__ __launch_bounds__(512, 4) void gemm2(
    const unsigned short* __restrict__ A, int lda,
    const unsigned short* __restrict__ W,
    const float* __restrict__ bias,
    const unsigned short* __restrict__ R, int ldr,
    const float* __restrict__ lng, const float* __restrict__ lnb,
    const float* __restrict__ qg, const float* __restrict__ qb,
    const float2* __restrict__ statsIn,
    const float* __restrict__ s1v, const float* __restrict__ s2v,
    unsigned short* __restrict__ C, int ldc) {
  __shared__ __attribute__((aligned(16))) unsigned short SMEM[36864];  // 72KB
  __shared__ float red1[128][4];
  __shared__ float red2[128][4];
  const int tid = threadIdx.x, lane = tid & 63, wid = tid >> 6;
  int m0, n0;
  if (G3) {
    int g = blockIdx.x / 24, sub = blockIdx.x % 24;
    m0 = (g * 8 + (sub & 7)) * 128;
    n0 = (sub >> 3) * 256;
  } else {
    m0 = blockIdx.x * 128;
    n0 = 0;
  }
  const int wm = wid >> 2, wn = wid & 3;
  const int lrow = lane & 15, kgrp = lane >> 4;
  const int srow = tid >> 2;
  const int sslot = (tid & 3) ^ (srow & 3);
  const unsigned short* gA  = A + (size_t)(m0 + srow) * lda + sslot * 8;
  const unsigned short* gW0 = W + (size_t)(n0 + srow) * kD + sslot * 8;
  const unsigned short* gW1 = gW0 + (size_t)128 * kD;
  const int sa = (kgrp ^ (lrow & 3)) * 8;

#define STAGE(kk, bb)                                                   \
  do {                                                                  \
    gload16(gA + (kk) * 32, &SMEM[(bb) * 4096 + wid * 512]);            \
    gload16(gW0 + (kk) * 32, &SMEM[12288 + (bb) * 8192 + wid * 512]);   \
    gload16(gW1 + (kk) * 32, &SMEM[16384 + (bb) * 8192 + wid * 512]);   \
  } while (0)

  f32x4 acc[4][4] = {};
  STAGE(0, 0);
  STAGE(1, 1);
#pragma unroll
  for (int k = 0; k < 8; ++k) {
    if (k < 7) vm3(); else vm0();
    bar();
    const int buf = k % 3;
    bf16x8 af[4], bfr[4];
#pragma unroll
    for (int x = 0; x < 4; ++x) {
      af[x]  = *reinterpret_cast<const bf16x8*>(
          &SMEM[12288 + buf * 8192 + (wn * 64 + x * 16 + lrow) * 32 + sa]);
      bfr[x] = *reinterpret_cast<const bf16x8*>(
          &SMEM[buf * 4096 + (wm * 64 + x * 16 + lrow) * 32 + sa]);
    }
    if (k + 2 < 8) STAGE(k + 2, (k + 2) % 3);
    __builtin_amdgcn_s_setprio(1);
#pragma unroll
    for (int na = 0; na < 4; ++na)
#pragma unroll
      for (int mb = 0; mb < 4; ++mb)
        acc[na][mb] = __builtin_amdgcn_mfma_f32_16x16x32_bf16(
            af[na], bfr[mb], acc[na][mb], 0, 0, 0);
    __builtin_amdgcn_s_setprio(0);
  }
#undef STAGE
  __syncthreads();
  const bool qpath = (MODE == 4) && (n0 == 0);
  float2 st[4];
  if (MODE == 5 || (MODE == 4 && n0 == 0)) {
#pragma unroll
    for (int mb = 0; mb < 4; ++mb)
      st[mb] = statsIn[m0 + wm * 64 + mb * 16 + lrow];
  }

  auto computeX = [&](int na, int mb, float x[4]) {
    const int gcol = n0 + wn * 64 + na * 16 + kgrp * 4;
    const f32x4 v = acc[na][mb];
    if (MODE == 4 && qpath) {
      float4 t1 = *reinterpret_cast<const float4*>(s1v + gcol);
      float4 t2 = *reinterpret_cast<const float4*>(s2v + gcol);
      const float s1f[4] = {t1.x, t1.y, t1.z, t1.w};
      const float s2f[4] = {t2.x, t2.y, t2.z, t2.w};
#pragma unroll
      for (int r = 0; r < 4; ++r)
        x[r] = st[mb].y * (v[r] - st[mb].x * s1f[r]) + s2f[r];
      return;
    }
    float4 b4 = *reinterpret_cast<const float4*>(bias + gcol);
    const float bx[4] = {b4.x, b4.y, b4.z, b4.w};
    if (MODE == 4) {
#pragma unroll
      for (int r = 0; r < 4; ++r) x[r] = v[r] + bx[r];
    } else {  // MODE 5
      int m = m0 + wm * 64 + mb * 16 + lrow;
      ushort4 rv = *reinterpret_cast<const ushort4*>(R + (size_t)m * ldr + gcol);
      const unsigned short* rs = reinterpret_cast<const unsigned short*>(&rv);
      float4 t1 = *reinterpret_cast<const float4*>(qg + gcol);
      float4 t2 = *reinterpret_cast<const float4*>(qb + gcol);
      const float g4[4] = {t1.x, t1.y, t1.z, t1.w};
      const float qb4[4] = {t2.x, t2.y, t2.z, t2.w};
#pragma unroll
      for (int r = 0; r < 4; ++r) {
        float q = (bf2f(rs[r]) - st[mb].x) * st[mb].y * g4[r] + qb4[r];
        x[r] = v[r] + bx[r] + q;
      }
    }
  };

  float mean[4], inv[4];
  if (LN) {
    float sA[4] = {0.f, 0.f, 0.f, 0.f}, sB[4] = {0.f, 0.f, 0.f, 0.f};
#pragma unroll
    for (int na = 0; na < 4; ++na)
#pragma unroll
      for (int mb = 0; mb < 4; ++mb) {
        float x[4];
        computeX(na, mb, x);
#pragma unroll
        for (int r = 0; r < 4; ++r) { sA[mb] += x[r]; sB[mb] += x[r] * x[r]; }
      }
#pragma unroll
    for (int mb = 0; mb < 4; ++mb) {
      sA[mb] += __shfl_xor(sA[mb], 16); sA[mb] += __shfl_xor(sA[mb], 32);
      sB[mb] += __shfl_xor(sB[mb], 16); sB[mb] += __shfl_xor(sB[mb], 32);
    }
    if (kgrp == 0) {
#pragma unroll
      for (int mb = 0; mb < 4; ++mb) {
        int rl = wm * 64 + mb * 16 + lrow;
        red1[rl][wn] = sA[mb];
        red2[rl][wn] = sB[mb];
      }
    }
    __syncthreads();
#pragma unroll
    for (int mb = 0; mb < 4; ++mb) {
      int rl = wm * 64 + mb * 16 + lrow;
      float4 p1 = *reinterpret_cast<const float4*>(red1[rl]);
      float4 p2 = *reinterpret_cast<const float4*>(red2[rl]);
      float t1 = p1.x + p1.y + p1.z + p1.w;
      float t2 = p2.x + p2.y + p2.z + p2.w;
      float mu = t1 * (1.f / 256.f);
      float var = t2 * (1.f / 256.f) - mu * mu;
      mean[mb] = mu;
      inv[mb] = rsqrtf(fmaxf(var, 0.f) + kEps);
    }
  }

  // ---- LDS-transposed store ----
  unsigned short* eb = &SMEM[wid * 3072];
  const int rr = lane >> 2, c8 = (lane & 3) * 8;
#pragma unroll
  for (int hh = 0; hh < 2; ++hh) {
    lk0();
#pragma unroll
    for (int mbl = 0; mbl < 2; ++mbl) {
      int mb = hh * 2 + mbl;
#pragma unroll
      for (int na = 0; na < 4; ++na) {
        float x[4];
        computeX(na, mb, x);
        if (LN == 1) {
          int gcol = n0 + wn * 64 + na * 16 + kgrp * 4;
          float4 g4v = *reinterpret_cast<const float4*>(lng + gcol);
          float4 b4v = *reinterpret_cast<const float4*>(lnb + gcol);
          x[0] = (x[0] - mean[mb]) * inv[mb] * g4v.x + b4v.x;
          x[1] = (x[1] - mean[mb]) * inv[mb] * g4v.y + b4v.y;
          x[2] = (x[2] - mean[mb]) * inv[mb] * g4v.z + b4v.z;
          x[3] = (x[3] - mean[mb]) * inv[mb] * g4v.w + b4v.w;
        }
        uint2 o = {cvtpk(x[0], x[1]), cvtpk(x[2], x[3])};
        *reinterpret_cast<uint2*>(&eb[(mbl * 16 + lrow) * 72 + na * 16 + kgrp * 4]) = o;
      }
    }
    lk0();
#pragma unroll
    for (int rh = 0; rh < 2; ++rh) {
      int row = rh * 16 + rr;
      uint4 d0 = *reinterpret_cast<const uint4*>(&eb[row * 72 + c8]);
      uint4 d1 = *reinterpret_cast<const uint4*>(&eb[row * 72 + 32 + c8]);
      size_t gbase = (size_t)(m0 + wm * 64 + hh * 32 + row) * ldc + (n0 + wn * 64 + c8);
      *reinterpret_cast<uint4*>(C + gbase) = d0;
      *reinterpret_cast<uint4*>(C + gbase + 32) = d1;
    }
  }
}

// ---------------- fused FFN: h1 = relu(A@c1^T+b1) in LDS; y = h1@c2^T+b2+A, *mask ----------------
// LAST=0: y computed ONCE into registers; write y + stats out.
// LAST=1: fused last-LN + logits (single pass, no C write).
template <int LAST>
__global__ __launch_bounds__(512, 4) void ffn_fused(
    const unsigned short* __restrict__ A, int lda,   // ln2out
    const unsigned short* __restrict__ W1, const float* __restrict__ b1,
    const unsigned short* __restrict__ W2, const float* __restrict__ b2,
    const int* __restrict__ logseq,
    const float* __restrict__ lng, const float* __restrict__ lnb,
    float2* __restrict__ statsOut,
    const float* __restrict__ iembf, const int* __restrict__ posq,
    const int* __restrict__ negq, float* __restrict__ outlg,
    unsigned short* __restrict__ C, int ldc) {
  // SMEM: As [2][2048] @0 | Ws [2][8192] @4096 | H1 [64][256] @20480  = 72KB
  __shared__ __attribute__((aligned(16))) unsigned short SMEM[36864];
  __shared__ float red1[64][4];
  __shared__ float red2[64][4];
  const int tid = threadIdx.x, lane = tid & 63, wid = tid >> 6;
  const int m0 = blockIdx.x * 64;
  const int wm = wid >> 2, wn = wid & 3;
  const int lrow = lane & 15, kgrp = lane >> 4;
  unsigned short* As = SMEM;
  unsigned short* Ws = SMEM + 4096;
  unsigned short* H1 = SMEM + 20480;
  const int arow = (wid & 3) * 16 + (lane >> 2);
  const int aslot = (lane & 3) ^ (arow & 3);
  const unsigned short* gA = A + (size_t)(m0 + arow) * lda + aslot * 8;
  const int wrow0 = wid * 32 + (lane >> 2);
  const int wrow1 = wrow0 + 16;
  const int ws0 = (lane & 3) ^ (wrow0 & 3);
  const int ws1 = (lane & 3) ^ (wrow1 & 3);
  const unsigned short* gW10 = W1 + wrow0 * 256 + ws0 * 8;
  const unsigned short* gW11 = W1 + wrow1 * 256 + ws1 * 8;
  const unsigned short* gW20 = W2 + wrow0 * 256 + ws0 * 8;
  const unsigned short* gW21 = W2 + wrow1 * 256 + ws1 * 8;
  const int sa = (kgrp ^ (lrow & 3)) * 8;
  const f32x4 zero = {0.f, 0.f, 0.f, 0.f};

#define STG1(kk, bb)                                               \
  do {                                                             \
    if (wid < 4) gload16(gA + (kk) * 32, &As[(bb) * 2048 + wid * 512]); \
    gload16(gW10 + (kk) * 32, &Ws[(bb) * 8192 + wid * 1024]);      \
    gload16(gW11 + (kk) * 32, &Ws[(bb) * 8192 + wid * 1024 + 512]);\
  } while (0)

  f32x4 acc[4][2] = {};
  STG1(0, 0);
  STG1(1, 1);
#pragma unroll
  for (int k = 0; k < 8; ++k) {
    if (k < 7) { if (wid < 4) vm3(); else vm2(); } else vm0();
    bar();
    const int buf = k & 1;
    bf16x8 af[4], bfr[2];
#pragma unroll
    for (int x = 0; x < 4; ++x)
      af[x] = *reinterpret_cast<const bf16x8*>(
          &Ws[buf * 8192 + (wn * 64 + x * 16 + lrow) * 32 + sa]);
#pragma unroll
    for (int mb = 0; mb < 2; ++mb)
      bfr[mb] = *reinterpret_cast<const bf16x8*>(
          &As[buf * 2048 + (wm * 32 + mb * 16 + lrow) * 32 + sa]);
    __builtin_amdgcn_s_setprio(1);
#pragma unroll
    for (int na = 0; na < 4; ++na)
#pragma unroll
      for (int mb = 0; mb < 2; ++mb)
        acc[na][mb] = __builtin_amdgcn_mfma_f32_16x16x32_bf16(
            af[na], bfr[mb], acc[na][mb], 0, 0, 0);
    __builtin_amdgcn_s_setprio(0);
    bar();
    if (k + 2 < 8) STG1(k + 2, k & 1);
  }
#undef STG1
  // h1 = relu(acc + b1) -> H1 (16B-slot XOR swizzle by row&7)
#pragma unroll
  for (int na = 0; na < 4; ++na) {
    int c0 = wn * 64 + na * 16 + kgrp * 4;
    float4 b4 = *reinterpret_cast<const float4*>(b1 + c0);
#pragma unroll
    for (int mb = 0; mb < 2; ++mb) {
      int row = wm * 32 + mb * 16 + lrow;
      f32x4 v = acc[na][mb];
      float x0 = fmaxf(v[0] + b4.x, 0.f), x1 = fmaxf(v[1] + b4.y, 0.f);
      float x2 = fmaxf(v[2] + b4.z, 0.f), x3 = fmaxf(v[3] + b4.w, 0.f);
      int s = wn * 8 + na * 2 + (kgrp >> 1);
      int addr = row * 256 + ((s ^ (row & 7)) << 3) + (kgrp & 1) * 4;
      uint2 o = {cvtpk(x0, x1), cvtpk(x2, x3)};
      *reinterpret_cast<uint2*>(&H1[addr]) = o;
    }
  }
  __syncthreads();
  // ---- phase 2: y = h1 @ c2^T ----
#pragma unroll
  for (int na = 0; na < 4; ++na)
#pragma unroll
    for (int mb = 0; mb < 2; ++mb) acc[na][mb] = zero;

#define STG2(kk, bb)                                               \
  do {                                                             \
    gload16(gW20 + (kk) * 32, &Ws[(bb) * 8192 + wid * 1024]);      \
    gload16(gW21 + (kk) * 32, &Ws[(bb) * 8192 + wid * 1024 + 512]);\
  } while (0)

  STG2(0, 0);
  STG2(1, 1);
#pragma unroll
  for (int k = 0; k < 8; ++k) {
    if (k < 7) vm2(); else vm0();
    bar();
    const int buf = k & 1;
    bf16x8 af[4], bfr[2];
#pragma unroll
    for (int x = 0; x < 4; ++x)
      af[x] = *reinterpret_cast<const bf16x8*>(
          &Ws[buf * 8192 + (wn * 64 + x * 16 + lrow) * 32 + sa]);
#pragma unroll
    for (int mb = 0; mb < 2; ++mb) {
      int row = wm * 32 + mb * 16 + lrow;
      bfr[mb] = *reinterpret_cast<const bf16x8*>(
          &H1[row * 256 + (((k * 4 + kgrp) ^ (row & 7)) << 3)]);
    }
    __builtin_amdgcn_s_setprio(1);
#pragma unroll
    for (int na = 0; na < 4; ++na)
#pragma unroll
      for (int mb = 0; mb < 2; ++mb)
        acc[na][mb] = __builtin_amdgcn_mfma_f32_16x16x32_bf16(
            af[na], bfr[mb], acc[na][mb], 0, 0, 0);
    __builtin_amdgcn_s_setprio(0);
    bar();
    if (k + 2 < 8) STG2(k + 2, k & 1);
  }
#undef STG2
  __syncthreads();  // staging dead -> reuse for SL/eb

  float msk[2];
#pragma unroll
  for (int mb = 0; mb < 2; ++mb)
    msk[mb] = (logseq[m0 + wm * 32 + mb * 16 + lrow] != 0) ? 1.f : 0.f;

  auto computeY = [&](int na, int mb, float x[4]) {
    int gcol = wn * 64 + na * 16 + kgrp * 4;
    int m = m0 + wm * 32 + mb * 16 + lrow;
    f32x4 v = acc[na][mb];
    float4 b4 = *reinterpret_cast<const float4*>(b2 + gcol);
    ushort4 rv = *reinterpret_cast<const ushort4*>(A + (size_t)m * lda + gcol);
    const unsigned short* rs = reinterpret_cast<const unsigned short*>(&rv);
    const float bx[4] = {b4.x, b4.y, b4.z, b4.w};
#pragma unroll
    for (int r = 0; r < 4; ++r)
      x[r] = (v[r] + bx[r] + bf2f(rs[r])) * msk[mb];
  };

  if (LAST == 0) {
    // y computed ONCE into registers (acc dead after)
    f32x4 yv[4][2];
#pragma unroll
    for (int na = 0; na < 4; ++na)
#pragma unroll
      for (int mb = 0; mb < 2; ++mb) {
        float x[4];
        computeY(na, mb, x);
        yv[na][mb][0] = x[0]; yv[na][mb][1] = x[1];
        yv[na][mb][2] = x[2]; yv[na][mb][3] = x[3];
      }
    float sA[2] = {0.f, 0.f}, sB[2] = {0.f, 0.f};
#pragma unroll
    for (int na = 0; na < 4; ++na)
#pragma unroll
      for (int mb = 0; mb < 2; ++mb)
#pragma unroll
        for (int r = 0; r < 4; ++r) {
          float x = yv[na][mb][r];
          sA[mb] += x;
          sB[mb] += x * x;
        }
#pragma unroll
    for (int mb = 0; mb < 2; ++mb) {
      sA[mb] += __shfl_xor(sA[mb], 16); sA[mb] += __shfl_xor(sA[mb], 32);
      sB[mb] += __shfl_xor(sB[mb], 16); sB[mb] += __shfl_xor(sB[mb], 32);
    }
    if (kgrp == 0) {
#pragma unroll
      for (int mb = 0; mb < 2; ++mb) {
        int rl = wm * 32 + mb * 16 + lrow;
        red1[rl][wn] = sA[mb];
        red2[rl][wn] = sB[mb];
      }
    }
    __syncthreads();
    if (wn == 0 && kgrp == 0) {
#pragma unroll
      for (int mb = 0; mb < 2; ++mb) {
        int rl = wm * 32 + mb * 16 + lrow;
        float4 p1 = *reinterpret_cast<const float4*>(red1[rl]);
        float4 p2 = *reinterpret_cast<const float4*>(red2[rl]);
        float t1 = p1.x + p1.y + p1.z + p1.w;
        float t2 = p2.x + p2.y + p2.z + p2.w;
        float mu = t1 * (1.f / 256.f);
        float var = t2 * (1.f / 256.f) - mu * mu;
        statsOut[m0 + rl] = {mu, rsqrtf(fmaxf(var, 0.f) + kEps)};
      }
    }
    unsigned short* eb = &SMEM[wid * 2560];
#pragma unroll
    for (int mb = 0; mb < 2; ++mb)
#pragma unroll
      for (int na = 0; na < 4; ++na) {
        uint2 o = {cvtpk(yv[na][mb][0], yv[na][mb][1]),
                   cvtpk(yv[na][mb][2], yv[na][mb][3])};
        *reinterpret_cast<uint2*>(&eb[(mb * 16 + lrow) * 72 + na * 16 + kgrp * 4]) = o;
      }
    lk0();
#pragma unroll
    for (int rh = 0; rh < 4; ++rh) {
      int row = rh * 8 + (lane >> 3);
      uint4 d = *reinterpret_cast<const uint4*>(&eb[row * 72 + (lane & 7) * 8]);
      *reinterpret_cast<uint4*>(
          C + (size_t)(m0 + wm * 32 + row) * ldc + wn * 64 + (lane & 7) * 8) = d;
    }
    return;
  }

  // ---- LAST=1: fused last-LN + logits (single pass) ----
  float* SL = reinterpret_cast<float*>(SMEM);  // [64][33]
  int pi[2], ni[2];
#pragma unroll
  for (int mb = 0; mb < 2; ++mb) {
    int m = m0 + wm * 32 + mb * 16 + lrow;
    pi[mb] = posq[m];
    ni[mb] = negq[m];
  }
#pragma unroll
  for (int mb = 0; mb < 2; ++mb) {
    float4 peL[4], neL[4];
#pragma unroll
    for (int na = 0; na < 4; ++na) {
      int gcol = wn * 64 + na * 16 + kgrp * 4;
      peL[na] = *reinterpret_cast<const float4*>(iembf + (size_t)pi[mb] * 256 + gcol);
      neL[na] = *reinterpret_cast<const float4*>(iembf + (size_t)ni[mb] * 256 + gcol);
    }
    float sa_ = 0.f, sb_ = 0.f;
    float s1p = 0.f, s2p = 0.f, s3p = 0.f;
    float s1n = 0.f, s2n = 0.f, s3n = 0.f;
#pragma unroll
    for (int na = 0; na < 4; ++na) {
      float x[4];
      computeY(na, mb, x);
      int gcol = wn * 64 + na * 16 + kgrp * 4;
      float4 g4v = *reinterpret_cast<const float4*>(lng + gcol);
      float4 b4v = *reinterpret_cast<const float4*>(lnb + gcol);
      const float gg[4] = {g4v.x, g4v.y, g4v.z, g4v.w};
      const float lb[4] = {b4v.x, b4v.y, b4v.z, b4v.w};
      const float pef[4] = {peL[na].x, peL[na].y, peL[na].z, peL[na].w};
      const float nef[4] = {neL[na].x, neL[na].y, neL[na].z, neL[na].w};
#pragma unroll
      for (int r = 0; r < 4; ++r) {
        sa_ += x[r];
        sb_ += x[r] * x[r];
        float gp = gg[r] * pef[r], gn = gg[r] * nef[r];
        s1p += x[r] * gp; s2p += gp; s3p += lb[r] * pef[r];
        s1n += x[r] * gn; s2n += gn; s3n += lb[r] * nef[r];
      }
    }
    float vals[8] = {sa_, sb_, s1p, s2p, s3p, s1n, s2n, s3n};
#pragma unroll
    for (int j = 0; j < 8; ++j) {
      vals[j] += __shfl_xor(vals[j], 16);
      vals[j] += __shfl_xor(vals[j], 32);
    }
    if (kgrp == 0) {
      int rl = wm * 32 + mb * 16 + lrow;
      float* dst = &SL[rl * 33 + wn * 8];
#pragma unroll
      for (int j = 0; j < 8; ++j) dst[j] = vals[j];
    }
  }
  __syncthreads();
  if (tid < 64) {
    float t[8] = {0.f, 0.f, 0.f, 0.f, 0.f, 0.f, 0.f, 0.f};
#pragma unroll
    for (int w = 0; w < 4; ++w) {
      const float* src = &SL[tid * 33 + w * 8];
#pragma unroll
      for (int j = 0; j < 8; ++j) t[j] += src[j];
    }
    float mean = t[0] * (1.f / 256.f);
    float var = t[1] * (1.f / 256.f) - mean * mean;
    float inv = rsqrtf(fmaxf(var, 0.f) + kEps);
    int m = m0 + tid;
    outlg[m] = inv * (t[2] - mean * t[3]) + t[4];
    outlg[(size_t)kM + m] = inv * (t[5] - mean * t[6]) + t[7];
  }
}

// ---------------- MFMA flash attention: 8 waves, fixed-max softmax ----------------
__global__ __launch_bounds__(512) void attn_mfma(unsigned short* __restrict__ qkv) {
  constexpr int kVS = 232, kQS = 768;
  __shared__ __attribute__((aligned(16))) unsigned short Kl[200 * 64];
  __shared__ __attribute__((aligned(16))) unsigned short Vt[64 * kVS];
  __shared__ __attribute__((aligned(16))) unsigned short Pt[8 * 636];
  int b = blockIdx.x >> 2, h = blockIdx.x & 3;
  int tid = threadIdx.x, lane = tid & 63, wid = tid >> 6;
  const unsigned short* kvb = qkv + (size_t)b * kS * kQS + 256 + h * 64;
  for (int i = tid; i < 1600; i += 512) {
    int row = i >> 3, slot = i & 7;
    *reinterpret_cast<uint4*>(&Kl[row * 64 + ((slot ^ (row & 7)) << 3)]) =
        *reinterpret_cast<const uint4*>(kvb + (size_t)row * kQS + slot * 8);
  }
  for (int i = tid; i < 3200; i += 512) {
    int row = i >> 4, d0 = (i & 15) * 4;
    ushort4 v = *reinterpret_cast<const ushort4*>(kvb + 256 + (size_t)row * kQS + d0);
    Vt[(d0 + 0) * kVS + row] = v.x;
    Vt[(d0 + 1) * kVS + row] = v.y;
    Vt[(d0 + 2) * kVS + row] = v.z;
    Vt[(d0 + 3) * kVS + row] = v.w;
  }
  for (int i = tid; i < 2048; i += 512) {
    int d = i >> 5, c = i & 31;
    Vt[d * kVS + 200 + c] = 0;
  }
  __syncthreads();

  int qcol = lane & 15, kgrp = lane >> 4;
  const float scale2 = 0.18033688f;  // (1/8) * log2(e)
  int packed = (wid < 3) ? (0xFFFC - wid) : (0xFF09 + (wid - 3) * 15);
  unsigned short* ptw = &Pt[wid * 636];
#pragma unroll
  for (int ti = 0; ti < 2; ++ti) {
    int t = (packed >> (ti * 4)) & 15;
    if (t == 15) break;
    int qb = t * 16;
    int qrow = qb + qcol;
    int qm = min(qrow, kS - 1);
    const unsigned short* qrp = qkv + (size_t)(b * kS + qm) * kQS + h * 64;
    bf16x8 qf0 = *reinterpret_cast<const bf16x8*>(qrp + kgrp * 8);
    bf16x8 qf1 = *reinterpret_cast<const bf16x8*>(qrp + 32 + kgrp * 8);
    f32x4 accO[4] = {};
    float l_run = 0.f;
    int nc = (qb + 47) >> 5;
    for (int c = 0; c < nc; ++c) {
      int kbase = c * 32;
      f32x4 s0 = {}, s1 = {};
      int kr0 = min(kbase + qcol, kS - 1);
      int kr1 = min(kbase + 16 + qcol, kS - 1);
      const unsigned short* K0a = &Kl[kr0 * 64 + ((kgrp ^ (kr0 & 7)) << 3)];
      const unsigned short* K0b = &Kl[kr0 * 64 + (((kgrp + 4) ^ (kr0 & 7)) << 3)];
      const unsigned short* K1a = &Kl[kr1 * 64 + ((kgrp ^ (kr1 & 7)) << 3)];
      const unsigned short* K1b = &Kl[kr1 * 64 + (((kgrp + 4) ^ (kr1 & 7)) << 3)];
      s0 = __builtin_amdgcn_mfma_f32_16x16x32_bf16(*reinterpret_cast<const bf16x8*>(K0a), qf0, s0, 0, 0, 0);
      s0 = __builtin_amdgcn_mfma_f32_16x16x32_bf16(*reinterpret_cast<const bf16x8*>(K0b), qf1, s0, 0, 0, 0);
      s1 = __builtin_amdgcn_mfma_f32_16x16x32_bf16(*reinterpret_cast<const bf16x8*>(K1a), qf0, s1, 0, 0, 0);
      s1 = __builtin_amdgcn_mfma_f32_16x16x32_bf16(*reinterpret_cast<const bf16x8*>(K1b), qf1, s1, 0, 0, 0);
      float p[8];
      float psum = 0.f;
#pragma unroll
      for (int r = 0; r < 4; ++r) {
        int key0 = kbase + kgrp * 4 + r;
        int key1 = key0 + 16;
        float x0 = (key0 <= qm) ? fmaf(s0[r], scale2, -8.f) : -3.0e38f;
        float x1 = (key1 <= qm) ? fmaf(s1[r], scale2, -8.f) : -3.0e38f;
        p[r] = exp2f(x0);
        p[r + 4] = exp2f(x1);
        psum += p[r] + p[r + 4];
      }
      l_run += psum;
      uint2 w0 = {cvtpk(p[0], p[1]), cvtpk(p[2], p[3])};
      uint2 w1 = {cvtpk(p[4], p[5]), cvtpk(p[6], p[7])};
      *reinterpret_cast<uint2*>(&ptw[qcol * 40 + kgrp * 4]) = w0;
      *reinterpret_cast<uint2*>(&ptw[qcol * 40 + 16 + kgrp * 4]) = w1;
      bf16x8 pf = *reinterpret_cast<const bf16x8*>(&ptw[qcol * 40 + kgrp * 8]);
#pragma unroll
      for (int nf = 0; nf < 4; ++nf) {
        bf16x8 vf = *reinterpret_cast<const bf16x8*>(
            &Vt[(nf * 16 + qcol) * kVS + kbase + kgrp * 8]);
        accO[nf] = __builtin_amdgcn_mfma_f32_16x16x32_bf16(vf, pf, accO[nf], 0, 0, 0);
      }
    }
    float l_tot = l_run;
    l_tot += __shfl_xor(l_tot, 16);
    l_tot += __shfl_xor(l_tot, 32);
    float inv = 1.f / l_tot;
    if (qrow < kS) {
      unsigned short* op = qkv + (size_t)(b * kS + qrow) * kQS + h * 64;
#pragma unroll
      for (int nf = 0; nf < 4; ++nf) {
        uint2 o4 = {cvtpk(accO[nf][0] * inv, accO[nf][1] * inv),
                    cvtpk(accO[nf][2] * inv, accO[nf][3] * inv)};
        *reinterpret_cast<uint2*>(op + nf * 16 + kgrp * 4) = o4;
      }
    }
  }
}

}  // namespace

extern "C" void kernel_launch(void* const* d_in, const int* in_sizes, int n_in,
                              void* d_out, int out_size, void* d_ws,
                              size_t ws_size, hipStream_t stream) {
  const float* item_emb = (const float*)d_in[0];
  const float* pos_emb  = (const float*)d_in[1];
  const float* ln1_g = (const float*)d_in[2];
  const float* ln1_b = (const float*)d_in[3];
  const float* in_w  = (const float*)d_in[4];   // [2,768,256]
  const float* in_b  = (const float*)d_in[5];   // [2,768]
  const float* out_w = (const float*)d_in[6];   // [2,256,256]
  const float* out_b = (const float*)d_in[7];
  const float* ln2_g = (const float*)d_in[8];
  const float* ln2_b = (const float*)d_in[9];
  const float* c1_w  = (const float*)d_in[10];
  const float* c1_b  = (const float*)d_in[11];
  const float* c2_w  = (const float*)d_in[12];
  const float* c2_b  = (const float*)d_in[13];
  const float* last_g = (const float*)d_in[14];
  const float* last_b = (const float*)d_in[15];
  const int* log_seqs = (const int*)d_in[17];
  const int* pos_seqs = (const int*)d_in[18];
  const int* neg_seqs = (const int*)d_in[19];
  float* out = (float*)d_out;

  size_t unit = (size_t)kM * kD;
  unsigned short* X   = (unsigned short*)d_ws;          // [M,256]
  unsigned short* QKV = X + unit;                       // [M,768]
  unsigned short* inw_bf  = X + 4 * unit;
  unsigned short* outw_bf = inw_bf + 2 * 768 * 256;
  unsigned short* c1w_bf  = outw_bf + 2 * 256 * 256;
  unsigned short* c2w_bf  = c1w_bf + 2 * 256 * 256;
  float2* stats = (float2*)(c2w_bf + 2 * 256 * 256);    // [2][M]
  float* s1buf = (float*)(stats + 2 * kM);              // [2][256]
  float* s2buf = s1buf + 512;

  cvt4_kernel<<<768, 256, 0, stream>>>(in_w, out_w, c1_w, c2_w, ln1_g,
                                       inw_bf, outw_bf, c1w_bf, c2w_bf);
  s1s2_kernel<<<512, 64, 0, stream>>>(in_w, in_b, ln1_g, ln1_b, s1buf, s2buf);
  embed_kernel<<<kM / 8, 512, 0, stream>>>(item_emb, pos_emb, log_seqs, X, stats);

  dim3 g1(kM / 128, 1);
  for (int l = 0; l < 2; ++l) {
    const unsigned short* iw = inw_bf + (size_t)l * 768 * 256;
    float2* stl = stats + (size_t)l * kM;
    // qkv = [q-affine(x) | x@Wk^T+bk | x@Wv^T+bv]
    gemm2<4, 0, 1><<<kM / 128 * 3, 512, 0, stream>>>(
        X, 256, iw, in_b + l * 768, nullptr, 0,
        nullptr, nullptr, nullptr, nullptr, stl,
        s1buf + l * 256, s2buf + l * 256, QKV, 768);
    attn_mfma<<<kB * kH, 512, 0, stream>>>(QKV);
    // ln2out = LN2(Qrec(x) + o@out_w^T + out_b)  -> QKV cols 256..511
    gemm2<5, 1, 0><<<g1, 512, 0, stream>>>(
        QKV, 768, outw_bf + (size_t)l * kD * kD, out_b + l * kD, X, 256,
        ln2_g + l * kD, ln2_b + l * kD, ln1_g + l * kD, ln1_b + l * kD,
        stl, nullptr, nullptr, QKV + 256, 768);
    if (l == 0) {
      ffn_fused<0><<<kM / 64, 512, 0, stream>>>(
          QKV + 256, 768, c1w_bf, c1_b, c2w_bf, c2_b, log_seqs,
          nullptr, nullptr, stats + kM, nullptr, nullptr, nullptr, nullptr,
          X, 256);
    } else {
      ffn_fused<1><<<kM / 64, 512, 0, stream>>>(
          QKV + 256, 768, c1w_bf + 65536, c1_b + 256, c2w_bf + 65536, c2_b + 256,
          log_seqs, last_g, last_b, nullptr, item_emb, pos_seqs, neg_seqs, out,
          nullptr, 0);
    }
  }
}

// Round 20
// 598.437 us; speedup vs baseline: 1.1851x; 1.0048x over previous
//
#include <hip/hip_runtime.h>
#include <math.h>

namespace {

constexpr int kB = 512, kS = 200, kD = 256, kH = 4;
constexpr int kM = kB * kS;           // 102400 rows
constexpr float kEps = 1e-8f;

typedef short bf16x8 __attribute__((ext_vector_type(8)));   // 8 bf16 = 4 VGPR
typedef float f32x4 __attribute__((ext_vector_type(4)));

__device__ __forceinline__ float bf2f(unsigned short s) {
  return __uint_as_float(((unsigned)s) << 16);
}
__device__ __forceinline__ unsigned cvtpk(float lo, float hi) {
  unsigned r;
  asm("v_cvt_pk_bf16_f32 %0, %1, %2" : "=v"(r) : "v"(lo), "v"(hi));
  return r;
}
__device__ __forceinline__ void gload16(const void* g, void* l) {
  __builtin_amdgcn_global_load_lds(
      (const __attribute__((address_space(1))) void*)g,
      (__attribute__((address_space(3))) void*)l, 16, 0, 0);
}
__device__ __forceinline__ void vm3() { asm volatile("s_waitcnt vmcnt(3)" ::: "memory"); }
__device__ __forceinline__ void vm2() { asm volatile("s_waitcnt vmcnt(2)" ::: "memory"); }
__device__ __forceinline__ void vm0() { asm volatile("s_waitcnt vmcnt(0)" ::: "memory"); }
__device__ __forceinline__ void lk0() { asm volatile("s_waitcnt lgkmcnt(0)" ::: "memory"); }
__device__ __forceinline__ void bar() { asm volatile("s_barrier" ::: "memory"); }

// ---------------- weights f32 -> bf16; q-rows of in_w get g-folded ----------------
__global__ __launch_bounds__(256) void cvt4_kernel(
    const float* __restrict__ w0, const float* __restrict__ w1,
    const float* __restrict__ w2, const float* __restrict__ w3,
    const float* __restrict__ ln1g,
    unsigned short* __restrict__ o0, unsigned short* __restrict__ o1,
    unsigned short* __restrict__ o2, unsigned short* __restrict__ o3) {
  int blk = blockIdx.x;
  const float* src;
  unsigned short* dst;
  int base;
  bool isin = false;
  if (blk < 384)      { src = w0; dst = o0; base = blk; isin = true; }
  else if (blk < 512) { src = w1; dst = o1; base = blk - 384; }
  else if (blk < 640) { src = w2; dst = o2; base = blk - 512; }
  else                { src = w3; dst = o3; base = blk - 640; }
  int i4 = (base * 256 + threadIdx.x) * 4;
  float4 v = *reinterpret_cast<const float4*>(src + i4);
  if (isin) {
    int layer = (i4 >= 196608) ? 1 : 0;
    int rem = i4 - layer * 196608;
    int n = rem >> 8;
    int k = rem & 255;
    if (n < 256) {
      float4 g = *reinterpret_cast<const float4*>(ln1g + layer * 256 + k);
      v.x *= g.x; v.y *= g.y; v.z *= g.z; v.w *= g.w;
    }
  }
  uint2 o = {cvtpk(v.x, v.y), cvtpk(v.z, v.w)};
  *reinterpret_cast<uint2*>(dst + i4) = o;
}

// s1[n] = sum_k Wq[n][k]*g[k];  s2[n] = sum_k Wq[n][k]*b[k] + bias_q[n]
__global__ __launch_bounds__(64) void s1s2_kernel(
    const float* __restrict__ in_w, const float* __restrict__ in_b,
    const float* __restrict__ ln1g, const float* __restrict__ ln1b,
    float* __restrict__ s1o, float* __restrict__ s2o) {
  int blk = blockIdx.x;
  int layer = blk >> 8, n = blk & 255;
  int k = threadIdx.x * 4;
  float4 w = *reinterpret_cast<const float4*>(in_w + (size_t)layer * 196608 + n * 256 + k);
  float4 g = *reinterpret_cast<const float4*>(ln1g + layer * 256 + k);
  float4 b = *reinterpret_cast<const float4*>(ln1b + layer * 256 + k);
  float a = w.x * g.x + w.y * g.y + w.z * g.z + w.w * g.w;
  float c = w.x * b.x + w.y * b.y + w.z * b.z + w.w * b.w;
#pragma unroll
  for (int o = 32; o >= 1; o >>= 1) { a += __shfl_xor(a, o); c += __shfl_xor(c, o); }
  if (threadIdx.x == 0) {
    s1o[blk] = a;
    s2o[blk] = c + in_b[layer * 768 + n];
  }
}

// ---------------- embed: x + LN1 row-stats; 8 rows/block ----------------
__global__ __launch_bounds__(512) void embed_kernel(
    const float* __restrict__ item_emb, const float* __restrict__ pos_emb,
    const int* __restrict__ log_seqs, unsigned short* __restrict__ x,
    float2* __restrict__ stats) {
  int bs = blockIdx.x * 8 + (threadIdx.x >> 6);
  int s = bs % kS;
  int idx = log_seqs[bs];
  float msk = (idx != 0) ? 1.f : 0.f;
  int t = threadIdx.x & 63;
  float4 a = reinterpret_cast<const float4*>(item_emb + (size_t)idx * kD)[t];
  float4 p = reinterpret_cast<const float4*>(pos_emb + (size_t)s * kD)[t];
  float v[4];
  v[0] = (a.x * 16.f + p.x) * msk;
  v[1] = (a.y * 16.f + p.y) * msk;
  v[2] = (a.z * 16.f + p.z) * msk;
  v[3] = (a.w * 16.f + p.w) * msk;
  uint2 r = {cvtpk(v[0], v[1]), cvtpk(v[2], v[3])};
  reinterpret_cast<uint2*>(x + (size_t)bs * kD)[t] = r;
  float sm = v[0] + v[1] + v[2] + v[3];
#pragma unroll
  for (int o = 32; o >= 1; o >>= 1) sm += __shfl_xor(sm, o);
  float mean = sm * (1.f / kD);
  float d0 = v[0] - mean, d1 = v[1] - mean, d2 = v[2] - mean, d3 = v[3] - mean;
  float vs = d0 * d0 + d1 * d1 + d2 * d2 + d3 * d3;
#pragma unroll
  for (int o = 32; o >= 1; o >>= 1) vs += __shfl_xor(vs, o);
  if (t == 0) stats[bs] = {mean, rsqrtf(vs * (1.f / kD) + kEps)};
}

// ---------------- fused MFMA GEMM (qkv / out-proj), 3-buffer, 1 barrier/step ----------------
// MODE: 4 qkv (y0 q-affine via stats/s1/s2, else +bias); 5 out-proj (+bias + Qrec)
// LN:   0 none; 1 C=LN(v)
// G3:   1 -> 1D grid 2400, XCD/time co-located y-partners (N=768)
template <int MODE, int LN, int G3>
__global__ __launch_bounds__(512, 4) void gemm2(
    const unsigned short* __restrict__ A, int lda,
    const unsigned short* __restrict__ W,
    const float* __restrict__ bias,
    const unsigned short* __restrict__ R, int ldr,
    const float* __restrict__ lng, const float* __restrict__ lnb,
    const float* __restrict__ qg, const float* __restrict__ qb,
    const float2* __restrict__ statsIn,
    const float* __restrict__ s1v, const float* __restrict__ s2v,
    unsigned short* __restrict__ C, int ldc) {
  __shared__ __attribute__((aligned(16))) unsigned short SMEM[36864];  // 72KB
  __shared__ float red1[128][4];
  __shared__ float red2[128][4];
  const int tid = threadIdx.x, lane = tid & 63, wid = tid >> 6;
  int m0, n0;
  if (G3) {
    int g = blockIdx.x / 24, sub = blockIdx.x % 24;
    m0 = (g * 8 + (sub & 7)) * 128;
    n0 = (sub >> 3) * 256;
  } else {
    m0 = blockIdx.x * 128;
    n0 = 0;
  }
  const int wm = wid >> 2, wn = wid & 3;
  const int lrow = lane & 15, kgrp = lane >> 4;
  const int srow = tid >> 2;
  const int sslot = (tid & 3) ^ (srow & 3);
  const unsigned short* gA  = A + (size_t)(m0 + srow) * lda + sslot * 8;
  const unsigned short* gW0 = W + (size_t)(n0 + srow) * kD + sslot * 8;
  const unsigned short* gW1 = gW0 + (size_t)128 * kD;
  const int sa = (kgrp ^ (lrow & 3)) * 8;

#define STAGE(kk, bb)                                                   \
  do {                                                                  \
    gload16(gA + (kk) * 32, &SMEM[(bb) * 4096 + wid * 512]);            \
    gload16(gW0 + (kk) * 32, &SMEM[12288 + (bb) * 8192 + wid * 512]);   \
    gload16(gW1 + (kk) * 32, &SMEM[16384 + (bb) * 8192 + wid * 512]);   \
  } while (0)

  f32x4 acc[4][4] = {};
  STAGE(0, 0);
  STAGE(1, 1);
#pragma unroll
  for (int k = 0; k < 8; ++k) {
    if (k < 7) vm3(); else vm0();
    bar();
    const int buf = k % 3;
    bf16x8 af[4], bfr[4];
#pragma unroll
    for (int x = 0; x < 4; ++x) {
      af[x]  = *reinterpret_cast<const bf16x8*>(
          &SMEM[12288 + buf * 8192 + (wn * 64 + x * 16 + lrow) * 32 + sa]);
      bfr[x] = *reinterpret_cast<const bf16x8*>(
          &SMEM[buf * 4096 + (wm * 64 + x * 16 + lrow) * 32 + sa]);
    }
    if (k + 2 < 8) STAGE(k + 2, (k + 2) % 3);
    __builtin_amdgcn_s_setprio(1);
#pragma unroll
    for (int na = 0; na < 4; ++na)
#pragma unroll
      for (int mb = 0; mb < 4; ++mb)
        acc[na][mb] = __builtin_amdgcn_mfma_f32_16x16x32_bf16(
            af[na], bfr[mb], acc[na][mb], 0, 0, 0);
    __builtin_amdgcn_s_setprio(0);
  }
#undef STAGE
  __syncthreads();
  const bool qpath = (MODE == 4) && (n0 == 0);
  float2 st[4];
  if (MODE == 5 || (MODE == 4 && n0 == 0)) {
#pragma unroll
    for (int mb = 0; mb < 4; ++mb)
      st[mb] = statsIn[m0 + wm * 64 + mb * 16 + lrow];
  }

  auto computeX = [&](int na, int mb, float x[4]) {
    const int gcol = n0 + wn * 64 + na * 16 + kgrp * 4;
    const f32x4 v = acc[na][mb];
    if (MODE == 4 && qpath) {
      float4 t1 = *reinterpret_cast<const float4*>(s1v + gcol);
      float4 t2 = *reinterpret_cast<const float4*>(s2v + gcol);
      const float s1f[4] = {t1.x, t1.y, t1.z, t1.w};
      const float s2f[4] = {t2.x, t2.y, t2.z, t2.w};
#pragma unroll
      for (int r = 0; r < 4; ++r)
        x[r] = st[mb].y * (v[r] - st[mb].x * s1f[r]) + s2f[r];
      return;
    }
    float4 b4 = *reinterpret_cast<const float4*>(bias + gcol);
    const float bx[4] = {b4.x, b4.y, b4.z, b4.w};
    if (MODE == 4) {
#pragma unroll
      for (int r = 0; r < 4; ++r) x[r] = v[r] + bx[r];
    } else {  // MODE 5
      int m = m0 + wm * 64 + mb * 16 + lrow;
      ushort4 rv = *reinterpret_cast<const ushort4*>(R + (size_t)m * ldr + gcol);
      const unsigned short* rs = reinterpret_cast<const unsigned short*>(&rv);
      float4 t1 = *reinterpret_cast<const float4*>(qg + gcol);
      float4 t2 = *reinterpret_cast<const float4*>(qb + gcol);
      const float g4[4] = {t1.x, t1.y, t1.z, t1.w};
      const float qb4[4] = {t2.x, t2.y, t2.z, t2.w};
#pragma unroll
      for (int r = 0; r < 4; ++r) {
        float q = (bf2f(rs[r]) - st[mb].x) * st[mb].y * g4[r] + qb4[r];
        x[r] = v[r] + bx[r] + q;
      }
    }
  };

  float mean[4], inv[4];
  if (LN) {
    float sA[4] = {0.f, 0.f, 0.f, 0.f}, sB[4] = {0.f, 0.f, 0.f, 0.f};
#pragma unroll
    for (int na = 0; na < 4; ++na)
#pragma unroll
      for (int mb = 0; mb < 4; ++mb) {
        float x[4];
        computeX(na, mb, x);
#pragma unroll
        for (int r = 0; r < 4; ++r) { sA[mb] += x[r]; sB[mb] += x[r] * x[r]; }
      }
#pragma unroll
    for (int mb = 0; mb < 4; ++mb) {
      sA[mb] += __shfl_xor(sA[mb], 16); sA[mb] += __shfl_xor(sA[mb], 32);
      sB[mb] += __shfl_xor(sB[mb], 16); sB[mb] += __shfl_xor(sB[mb], 32);
    }
    if (kgrp == 0) {
#pragma unroll
      for (int mb = 0; mb < 4; ++mb) {
        int rl = wm * 64 + mb * 16 + lrow;
        red1[rl][wn] = sA[mb];
        red2[rl][wn] = sB[mb];
      }
    }
    __syncthreads();
#pragma unroll
    for (int mb = 0; mb < 4; ++mb) {
      int rl = wm * 64 + mb * 16 + lrow;
      float4 p1 = *reinterpret_cast<const float4*>(red1[rl]);
      float4 p2 = *reinterpret_cast<const float4*>(red2[rl]);
      float t1 = p1.x + p1.y + p1.z + p1.w;
      float t2 = p2.x + p2.y + p2.z + p2.w;
      float mu = t1 * (1.f / 256.f);
      float var = t2 * (1.f / 256.f) - mu * mu;
      mean[mb] = mu;
      inv[mb] = rsqrtf(fmaxf(var, 0.f) + kEps);
    }
  }

  // ---- LDS-transposed store ----
  unsigned short* eb = &SMEM[wid * 3072];
  const int rr = lane >> 2, c8 = (lane & 3) * 8;
#pragma unroll
  for (int hh = 0; hh < 2; ++hh) {
    lk0();
#pragma unroll
    for (int mbl = 0; mbl < 2; ++mbl) {
      int mb = hh * 2 + mbl;
#pragma unroll
      for (int na = 0; na < 4; ++na) {
        float x[4];
        computeX(na, mb, x);
        if (LN == 1) {
          int gcol = n0 + wn * 64 + na * 16 + kgrp * 4;
          float4 g4v = *reinterpret_cast<const float4*>(lng + gcol);
          float4 b4v = *reinterpret_cast<const float4*>(lnb + gcol);
          x[0] = (x[0] - mean[mb]) * inv[mb] * g4v.x + b4v.x;
          x[1] = (x[1] - mean[mb]) * inv[mb] * g4v.y + b4v.y;
          x[2] = (x[2] - mean[mb]) * inv[mb] * g4v.z + b4v.z;
          x[3] = (x[3] - mean[mb]) * inv[mb] * g4v.w + b4v.w;
        }
        uint2 o = {cvtpk(x[0], x[1]), cvtpk(x[2], x[3])};
        *reinterpret_cast<uint2*>(&eb[(mbl * 16 + lrow) * 72 + na * 16 + kgrp * 4]) = o;
      }
    }
    lk0();
#pragma unroll
    for (int rh = 0; rh < 2; ++rh) {
      int row = rh * 16 + rr;
      uint4 d0 = *reinterpret_cast<const uint4*>(&eb[row * 72 + c8]);
      uint4 d1 = *reinterpret_cast<const uint4*>(&eb[row * 72 + 32 + c8]);
      size_t gbase = (size_t)(m0 + wm * 64 + hh * 32 + row) * ldc + (n0 + wn * 64 + c8);
      *reinterpret_cast<uint4*>(C + gbase) = d0;
      *reinterpret_cast<uint4*>(C + gbase + 32) = d1;
    }
  }
}

// ---------------- fused FFN: h1 = relu(A@c1^T+b1) in LDS; y = h1@c2^T+b2+A, *mask ----------------
// LAST=0: y computed ONCE into registers; write y + stats out.
// LAST=1: fused last-LN + logits (single pass, no C write).
template <int LAST>
__global__ __launch_bounds__(512, 4) void ffn_fused(
    const unsigned short* __restrict__ A, int lda,   // ln2out
    const unsigned short* __restrict__ W1, const float* __restrict__ b1,
    const unsigned short* __restrict__ W2, const float* __restrict__ b2,
    const int* __restrict__ logseq,
    const float* __restrict__ lng, const float* __restrict__ lnb,
    float2* __restrict__ statsOut,
    const float* __restrict__ iembf, const int* __restrict__ posq,
    const int* __restrict__ negq, float* __restrict__ outlg,
    unsigned short* __restrict__ C, int ldc) {
  // SMEM: As [2][2048] @0 | Ws [2][8192] @4096 | H1 [64][256] @20480  = 72KB
  __shared__ __attribute__((aligned(16))) unsigned short SMEM[36864];
  __shared__ float red1[64][4];
  __shared__ float red2[64][4];
  const int tid = threadIdx.x, lane = tid & 63, wid = tid >> 6;
  const int m0 = blockIdx.x * 64;
  const int wm = wid >> 2, wn = wid & 3;
  const int lrow = lane & 15, kgrp = lane >> 4;
  unsigned short* As = SMEM;
  unsigned short* Ws = SMEM + 4096;
  unsigned short* H1 = SMEM + 20480;
  const int arow = (wid & 3) * 16 + (lane >> 2);
  const int aslot = (lane & 3) ^ (arow & 3);
  const unsigned short* gA = A + (size_t)(m0 + arow) * lda + aslot * 8;
  const int wrow0 = wid * 32 + (lane >> 2);
  const int wrow1 = wrow0 + 16;
  const int ws0 = (lane & 3) ^ (wrow0 & 3);
  const int ws1 = (lane & 3) ^ (wrow1 & 3);
  const unsigned short* gW10 = W1 + wrow0 * 256 + ws0 * 8;
  const unsigned short* gW11 = W1 + wrow1 * 256 + ws1 * 8;
  const unsigned short* gW20 = W2 + wrow0 * 256 + ws0 * 8;
  const unsigned short* gW21 = W2 + wrow1 * 256 + ws1 * 8;
  const int sa = (kgrp ^ (lrow & 3)) * 8;
  const f32x4 zero = {0.f, 0.f, 0.f, 0.f};

#define STG1(kk, bb)                                               \
  do {                                                             \
    if (wid < 4) gload16(gA + (kk) * 32, &As[(bb) * 2048 + wid * 512]); \
    gload16(gW10 + (kk) * 32, &Ws[(bb) * 8192 + wid * 1024]);      \
    gload16(gW11 + (kk) * 32, &Ws[(bb) * 8192 + wid * 1024 + 512]);\
  } while (0)

  f32x4 acc[4][2] = {};
  STG1(0, 0);
  STG1(1, 1);
#pragma unroll
  for (int k = 0; k < 8; ++k) {
    if (k < 7) { if (wid < 4) vm3(); else vm2(); } else vm0();
    bar();
    const int buf = k & 1;
    bf16x8 af[4], bfr[2];
#pragma unroll
    for (int x = 0; x < 4; ++x)
      af[x] = *reinterpret_cast<const bf16x8*>(
          &Ws[buf * 8192 + (wn * 64 + x * 16 + lrow) * 32 + sa]);
#pragma unroll
    for (int mb = 0; mb < 2; ++mb)
      bfr[mb] = *reinterpret_cast<const bf16x8*>(
          &As[buf * 2048 + (wm * 32 + mb * 16 + lrow) * 32 + sa]);
    __builtin_amdgcn_s_setprio(1);
#pragma unroll
    for (int na = 0; na < 4; ++na)
#pragma unroll
      for (int mb = 0; mb < 2; ++mb)
        acc[na][mb] = __builtin_amdgcn_mfma_f32_16x16x32_bf16(
            af[na], bfr[mb], acc[na][mb], 0, 0, 0);
    __builtin_amdgcn_s_setprio(0);
    bar();
    if (k + 2 < 8) STG1(k + 2, k & 1);
  }
#undef STG1
  // h1 = relu(acc + b1) -> H1 (16B-slot XOR swizzle by row&7)
#pragma unroll
  for (int na = 0; na < 4; ++na) {
    int c0 = wn * 64 + na * 16 + kgrp * 4;
    float4 b4 = *reinterpret_cast<const float4*>(b1 + c0);
#pragma unroll
    for (int mb = 0; mb < 2; ++mb) {
      int row = wm * 32 + mb * 16 + lrow;
      f32x4 v = acc[na][mb];
      float x0 = fmaxf(v[0] + b4.x, 0.f), x1 = fmaxf(v[1] + b4.y, 0.f);
      float x2 = fmaxf(v[2] + b4.z, 0.f), x3 = fmaxf(v[3] + b4.w, 0.f);
      int s = wn * 8 + na * 2 + (kgrp >> 1);
      int addr = row * 256 + ((s ^ (row & 7)) << 3) + (kgrp & 1) * 4;
      uint2 o = {cvtpk(x0, x1), cvtpk(x2, x3)};
      *reinterpret_cast<uint2*>(&H1[addr]) = o;
    }
  }
  __syncthreads();
  // ---- phase 2: y = h1 @ c2^T ----
#pragma unroll
  for (int na = 0; na < 4; ++na)
#pragma unroll
    for (int mb = 0; mb < 2; ++mb) acc[na][mb] = zero;

#define STG2(kk, bb)                                               \
  do {                                                             \
    gload16(gW20 + (kk) * 32, &Ws[(bb) * 8192 + wid * 1024]);      \
    gload16(gW21 + (kk) * 32, &Ws[(bb) * 8192 + wid * 1024 + 512]);\
  } while (0)

  STG2(0, 0);
  STG2(1, 1);
#pragma unroll
  for (int k = 0; k < 8; ++k) {
    if (k < 7) vm2(); else vm0();
    bar();
    const int buf = k & 1;
    bf16x8 af[4], bfr[2];
#pragma unroll
    for (int x = 0; x < 4; ++x)
      af[x] = *reinterpret_cast<const bf16x8*>(
          &Ws[buf * 8192 + (wn * 64 + x * 16 + lrow) * 32 + sa]);
#pragma unroll
    for (int mb = 0; mb < 2; ++mb) {
      int row = wm * 32 + mb * 16 + lrow;
      bfr[mb] = *reinterpret_cast<const bf16x8*>(
          &H1[row * 256 + (((k * 4 + kgrp) ^ (row & 7)) << 3)]);
    }
    __builtin_amdgcn_s_setprio(1);
#pragma unroll
    for (int na = 0; na < 4; ++na)
#pragma unroll
      for (int mb = 0; mb < 2; ++mb)
        acc[na][mb] = __builtin_amdgcn_mfma_f32_16x16x32_bf16(
            af[na], bfr[mb], acc[na][mb], 0, 0, 0);
    __builtin_amdgcn_s_setprio(0);
    bar();
    if (k + 2 < 8) STG2(k + 2, k & 1);
  }
#undef STG2
  __syncthreads();  // staging dead -> reuse for SL/eb

  float msk[2];
#pragma unroll
  for (int mb = 0; mb < 2; ++mb)
    msk[mb] = (logseq[m0 + wm * 32 + mb * 16 + lrow] != 0) ? 1.f : 0.f;

  auto computeY = [&](int na, int mb, float x[4]) {
    int gcol = wn * 64 + na * 16 + kgrp * 4;
    int m = m0 + wm * 32 + mb * 16 + lrow;
    f32x4 v = acc[na][mb];
    float4 b4 = *reinterpret_cast<const float4*>(b2 + gcol);
    ushort4 rv = *reinterpret_cast<const ushort4*>(A + (size_t)m * lda + gcol);
    const unsigned short* rs = reinterpret_cast<const unsigned short*>(&rv);
    const float bx[4] = {b4.x, b4.y, b4.z, b4.w};
#pragma unroll
    for (int r = 0; r < 4; ++r)
      x[r] = (v[r] + bx[r] + bf2f(rs[r])) * msk[mb];
  };

  if (LAST == 0) {
    f32x4 yv[4][2];
#pragma unroll
    for (int na = 0; na < 4; ++na)
#pragma unroll
      for (int mb = 0; mb < 2; ++mb) {
        float x[4];
        computeY(na, mb, x);
        yv[na][mb][0] = x[0]; yv[na][mb][1] = x[1];
        yv[na][mb][2] = x[2]; yv[na][mb][3] = x[3];
      }
    float sA[2] = {0.f, 0.f}, sB[2] = {0.f, 0.f};
#pragma unroll
    for (int na = 0; na < 4; ++na)
#pragma unroll
      for (int mb = 0; mb < 2; ++mb)
#pragma unroll
        for (int r = 0; r < 4; ++r) {
          float x = yv[na][mb][r];
          sA[mb] += x;
          sB[mb] += x * x;
        }
#pragma unroll
    for (int mb = 0; mb < 2; ++mb) {
      sA[mb] += __shfl_xor(sA[mb], 16); sA[mb] += __shfl_xor(sA[mb], 32);
      sB[mb] += __shfl_xor(sB[mb], 16); sB[mb] += __shfl_xor(sB[mb], 32);
    }
    if (kgrp == 0) {
#pragma unroll
      for (int mb = 0; mb < 2; ++mb) {
        int rl = wm * 32 + mb * 16 + lrow;
        red1[rl][wn] = sA[mb];
        red2[rl][wn] = sB[mb];
      }
    }
    __syncthreads();
    if (wn == 0 && kgrp == 0) {
#pragma unroll
      for (int mb = 0; mb < 2; ++mb) {
        int rl = wm * 32 + mb * 16 + lrow;
        float4 p1 = *reinterpret_cast<const float4*>(red1[rl]);
        float4 p2 = *reinterpret_cast<const float4*>(red2[rl]);
        float t1 = p1.x + p1.y + p1.z + p1.w;
        float t2 = p2.x + p2.y + p2.z + p2.w;
        float mu = t1 * (1.f / 256.f);
        float var = t2 * (1.f / 256.f) - mu * mu;
        statsOut[m0 + rl] = {mu, rsqrtf(fmaxf(var, 0.f) + kEps)};
      }
    }
    unsigned short* eb = &SMEM[wid * 2560];
#pragma unroll
    for (int mb = 0; mb < 2; ++mb)
#pragma unroll
      for (int na = 0; na < 4; ++na) {
        uint2 o = {cvtpk(yv[na][mb][0], yv[na][mb][1]),
                   cvtpk(yv[na][mb][2], yv[na][mb][3])};
        *reinterpret_cast<uint2*>(&eb[(mb * 16 + lrow) * 72 + na * 16 + kgrp * 4]) = o;
      }
    lk0();
#pragma unroll
    for (int rh = 0; rh < 4; ++rh) {
      int row = rh * 8 + (lane >> 3);
      uint4 d = *reinterpret_cast<const uint4*>(&eb[row * 72 + (lane & 7) * 8]);
      *reinterpret_cast<uint4*>(
          C + (size_t)(m0 + wm * 32 + row) * ldc + wn * 64 + (lane & 7) * 8) = d;
    }
    return;
  }

  // ---- LAST=1: fused last-LN + logits (single pass) ----
  float* SL = reinterpret_cast<float*>(SMEM);  // [64][33]
  int pi[2], ni[2];
#pragma unroll
  for (int mb = 0; mb < 2; ++mb) {
    int m = m0 + wm * 32 + mb * 16 + lrow;
    pi[mb] = posq[m];
    ni[mb] = negq[m];
  }
#pragma unroll
  for (int mb = 0; mb < 2; ++mb) {
    float4 peL[4], neL[4];
#pragma unroll
    for (int na = 0; na < 4; ++na) {
      int gcol = wn * 64 + na * 16 + kgrp * 4;
      peL[na] = *reinterpret_cast<const float4*>(iembf + (size_t)pi[mb] * 256 + gcol);
      neL[na] = *reinterpret_cast<const float4*>(iembf + (size_t)ni[mb] * 256 + gcol);
    }
    float sa_ = 0.f, sb_ = 0.f;
    float s1p = 0.f, s2p = 0.f, s3p = 0.f;
    float s1n = 0.f, s2n = 0.f, s3n = 0.f;
#pragma unroll
    for (int na = 0; na < 4; ++na) {
      float x[4];
      computeY(na, mb, x);
      int gcol = wn * 64 + na * 16 + kgrp * 4;
      float4 g4v = *reinterpret_cast<const float4*>(lng + gcol);
      float4 b4v = *reinterpret_cast<const float4*>(lnb + gcol);
      const float gg[4] = {g4v.x, g4v.y, g4v.z, g4v.w};
      const float lb[4] = {b4v.x, b4v.y, b4v.z, b4v.w};
      const float pef[4] = {peL[na].x, peL[na].y, peL[na].z, peL[na].w};
      const float nef[4] = {neL[na].x, neL[na].y, neL[na].z, neL[na].w};
#pragma unroll
      for (int r = 0; r < 4; ++r) {
        sa_ += x[r];
        sb_ += x[r] * x[r];
        float gp = gg[r] * pef[r], gn = gg[r] * nef[r];
        s1p += x[r] * gp; s2p += gp; s3p += lb[r] * pef[r];
        s1n += x[r] * gn; s2n += gn; s3n += lb[r] * nef[r];
      }
    }
    float vals[8] = {sa_, sb_, s1p, s2p, s3p, s1n, s2n, s3n};
#pragma unroll
    for (int j = 0; j < 8; ++j) {
      vals[j] += __shfl_xor(vals[j], 16);
      vals[j] += __shfl_xor(vals[j], 32);
    }
    if (kgrp == 0) {
      int rl = wm * 32 + mb * 16 + lrow;
      float* dst = &SL[rl * 33 + wn * 8];
#pragma unroll
      for (int j = 0; j < 8; ++j) dst[j] = vals[j];
    }
  }
  __syncthreads();
  if (tid < 64) {
    float t[8] = {0.f, 0.f, 0.f, 0.f, 0.f, 0.f, 0.f, 0.f};
#pragma unroll
    for (int w = 0; w < 4; ++w) {
      const float* src = &SL[tid * 33 + w * 8];
#pragma unroll
      for (int j = 0; j < 8; ++j) t[j] += src[j];
    }
    float mean = t[0] * (1.f / 256.f);
    float var = t[1] * (1.f / 256.f) - mean * mean;
    float inv = rsqrtf(fmaxf(var, 0.f) + kEps);
    int m = m0 + tid;
    outlg[m] = inv * (t[2] - mean * t[3]) + t[4];
    outlg[(size_t)kM + m] = inv * (t[5] - mean * t[6]) + t[7];
  }
}

// ---------------- MFMA flash attention: 8 waves, fixed-max softmax ----------------
// XCD-grouped block remap: the 4 h-blocks of one b share bid mod 8 (same XCD L2).
__global__ __launch_bounds__(512) void attn_mfma(unsigned short* __restrict__ qkv) {
  constexpr int kVS = 232, kQS = 768;
  __shared__ __attribute__((aligned(16))) unsigned short Kl[200 * 64];
  __shared__ __attribute__((aligned(16))) unsigned short Vt[64 * kVS];
  __shared__ __attribute__((aligned(16))) unsigned short Pt[8 * 636];
  int bid = blockIdx.x;
  int h = (bid >> 3) & 3;
  int b = (bid & 7) | ((bid >> 5) << 3);
  int tid = threadIdx.x, lane = tid & 63, wid = tid >> 6;
  const unsigned short* kvb = qkv + (size_t)b * kS * kQS + 256 + h * 64;
  for (int i = tid; i < 1600; i += 512) {
    int row = i >> 3, slot = i & 7;
    *reinterpret_cast<uint4*>(&Kl[row * 64 + ((slot ^ (row & 7)) << 3)]) =
        *reinterpret_cast<const uint4*>(kvb + (size_t)row * kQS + slot * 8);
  }
  for (int i = tid; i < 3200; i += 512) {
    int row = i >> 4, d0 = (i & 15) * 4;
    ushort4 v = *reinterpret_cast<const ushort4*>(kvb + 256 + (size_t)row * kQS + d0);
    Vt[(d0 + 0) * kVS + row] = v.x;
    Vt[(d0 + 1) * kVS + row] = v.y;
    Vt[(d0 + 2) * kVS + row] = v.z;
    Vt[(d0 + 3) * kVS + row] = v.w;
  }
  for (int i = tid; i < 2048; i += 512) {
    int d = i >> 5, c = i & 31;
    Vt[d * kVS + 200 + c] = 0;
  }
  __syncthreads();

  int qcol = lane & 15, kgrp = lane >> 4;
  const float scale2 = 0.18033688f;  // (1/8) * log2(e)
  int packed = (wid < 3) ? (0xFFFC - wid) : (0xFF09 + (wid - 3) * 15);
  unsigned short* ptw = &Pt[wid * 636];
#pragma unroll
  for (int ti = 0; ti < 2; ++ti) {
    int t = (packed >> (ti * 4)) & 15;
    if (t == 15) break;
    int qb = t * 16;
    int qrow = qb + qcol;
    int qm = min(qrow, kS - 1);
    const unsigned short* qrp = qkv + (size_t)(b * kS + qm) * kQS + h * 64;
    bf16x8 qf0 = *reinterpret_cast<const bf16x8*>(qrp + kgrp * 8);
    bf16x8 qf1 = *reinterpret_cast<const bf16x8*>(qrp + 32 + kgrp * 8);
    f32x4 accO[4] = {};
    float l_run = 0.f;
    int nc = (qb + 47) >> 5;
    for (int c = 0; c < nc; ++c) {
      int kbase = c * 32;
      f32x4 s0 = {}, s1 = {};
      int kr0 = min(kbase + qcol, kS - 1);
      int kr1 = min(kbase + 16 + qcol, kS - 1);
      const unsigned short* K0a = &Kl[kr0 * 64 + ((kgrp ^ (kr0 & 7)) << 3)];
      const unsigned short* K0b = &Kl[kr0 * 64 + (((kgrp + 4) ^ (kr0 & 7)) << 3)];
      const unsigned short* K1a = &Kl[kr1 * 64 + ((kgrp ^ (kr1 & 7)) << 3)];
      const unsigned short* K1b = &Kl[kr1 * 64 + (((kgrp + 4) ^ (kr1 & 7)) << 3)];
      s0 = __builtin_amdgcn_mfma_f32_16x16x32_bf16(*reinterpret_cast<const bf16x8*>(K0a), qf0, s0, 0, 0, 0);
      s0 = __builtin_amdgcn_mfma_f32_16x16x32_bf16(*reinterpret_cast<const bf16x8*>(K0b), qf1, s0, 0, 0, 0);
      s1 = __builtin_amdgcn_mfma_f32_16x16x32_bf16(*reinterpret_cast<const bf16x8*>(K1a), qf0, s1, 0, 0, 0);
      s1 = __builtin_amdgcn_mfma_f32_16x16x32_bf16(*reinterpret_cast<const bf16x8*>(K1b), qf1, s1, 0, 0, 0);
      float p[8];
      float psum = 0.f;
#pragma unroll
      for (int r = 0; r < 4; ++r) {
        int key0 = kbase + kgrp * 4 + r;
        int key1 = key0 + 16;
        float x0 = (key0 <= qm) ? fmaf(s0[r], scale2, -8.f) : -3.0e38f;
        float x1 = (key1 <= qm) ? fmaf(s1[r], scale2, -8.f) : -3.0e38f;
        p[r] = exp2f(x0);
        p[r + 4] = exp2f(x1);
        psum += p[r] + p[r + 4];
      }
      l_run += psum;
      uint2 w0 = {cvtpk(p[0], p[1]), cvtpk(p[2], p[3])};
      uint2 w1 = {cvtpk(p[4], p[5]), cvtpk(p[6], p[7])};
      *reinterpret_cast<uint2*>(&ptw[qcol * 40 + kgrp * 4]) = w0;
      *reinterpret_cast<uint2*>(&ptw[qcol * 40 + 16 + kgrp * 4]) = w1;
      bf16x8 pf = *reinterpret_cast<const bf16x8*>(&ptw[qcol * 40 + kgrp * 8]);
#pragma unroll
      for (int nf = 0; nf < 4; ++nf) {
        bf16x8 vf = *reinterpret_cast<const bf16x8*>(
            &Vt[(nf * 16 + qcol) * kVS + kbase + kgrp * 8]);
        accO[nf] = __builtin_amdgcn_mfma_f32_16x16x32_bf16(vf, pf, accO[nf], 0, 0, 0);
      }
    }
    float l_tot = l_run;
    l_tot += __shfl_xor(l_tot, 16);
    l_tot += __shfl_xor(l_tot, 32);
    float inv = 1.f / l_tot;
    if (qrow < kS) {
      unsigned short* op = qkv + (size_t)(b * kS + qrow) * kQS + h * 64;
#pragma unroll
      for (int nf = 0; nf < 4; ++nf) {
        uint2 o4 = {cvtpk(accO[nf][0] * inv, accO[nf][1] * inv),
                    cvtpk(accO[nf][2] * inv, accO[nf][3] * inv)};
        *reinterpret_cast<uint2*>(op + nf * 16 + kgrp * 4) = o4;
      }
    }
  }
}

}  // namespace

extern "C" void kernel_launch(void* const* d_in, const int* in_sizes, int n_in,
                              void* d_out, int out_size, void* d_ws,
                              size_t ws_size, hipStream_t stream) {
  const float* item_emb = (const float*)d_in[0];
  const float* pos_emb  = (const float*)d_in[1];
  const float* ln1_g = (const float*)d_in[2];
  const float* ln1_b = (const float*)d_in[3];
  const float* in_w  = (const float*)d_in[4];   // [2,768,256]
  const float* in_b  = (const float*)d_in[5];   // [2,768]
  const float* out_w = (const float*)d_in[6];   // [2,256,256]
  const float* out_b = (const float*)d_in[7];
  const float* ln2_g = (const float*)d_in[8];
  const float* ln2_b = (const float*)d_in[9];
  const float* c1_w  = (const float*)d_in[10];
  const float* c1_b  = (const float*)d_in[11];
  const float* c2_w  = (const float*)d_in[12];
  const float* c2_b  = (const float*)d_in[13];
  const float* last_g = (const float*)d_in[14];
  const float* last_b = (const float*)d_in[15];
  const int* log_seqs = (const int*)d_in[17];
  const int* pos_seqs = (const int*)d_in[18];
  const int* neg_seqs = (const int*)d_in[19];
  float* out = (float*)d_out;

  size_t unit = (size_t)kM * kD;
  unsigned short* X   = (unsigned short*)d_ws;          // [M,256]
  unsigned short* QKV = X + unit;                       // [M,768]
  unsigned short* inw_bf  = X + 4 * unit;
  unsigned short* outw_bf = inw_bf + 2 * 768 * 256;
  unsigned short* c1w_bf  = outw_bf + 2 * 256 * 256;
  unsigned short* c2w_bf  = c1w_bf + 2 * 256 * 256;
  float2* stats = (float2*)(c2w_bf + 2 * 256 * 256);    // [2][M]
  float* s1buf = (float*)(stats + 2 * kM);              // [2][256]
  float* s2buf = s1buf + 512;

  cvt4_kernel<<<768, 256, 0, stream>>>(in_w, out_w, c1_w, c2_w, ln1_g,
                                       inw_bf, outw_bf, c1w_bf, c2w_bf);
  s1s2_kernel<<<512, 64, 0, stream>>>(in_w, in_b, ln1_g, ln1_b, s1buf, s2buf);
  embed_kernel<<<kM / 8, 512, 0, stream>>>(item_emb, pos_emb, log_seqs, X, stats);

  dim3 g1(kM / 128, 1);
  for (int l = 0; l < 2; ++l) {
    const unsigned short* iw = inw_bf + (size_t)l * 768 * 256;
    float2* stl = stats + (size_t)l * kM;
    // qkv = [q-affine(x) | x@Wk^T+bk | x@Wv^T+bv]
    gemm2<4, 0, 1><<<kM / 128 * 3, 512, 0, stream>>>(
        X, 256, iw, in_b + l * 768, nullptr, 0,
        nullptr, nullptr, nullptr, nullptr, stl,
        s1buf + l * 256, s2buf + l * 256, QKV, 768);
    attn_mfma<<<kB * kH, 512, 0, stream>>>(QKV);
    // ln2out = LN2(Qrec(x) + o@out_w^T + out_b)  -> QKV cols 256..511
    gemm2<5, 1, 0><<<g1, 512, 0, stream>>>(
        QKV, 768, outw_bf + (size_t)l * kD * kD, out_b + l * kD, X, 256,
        ln2_g + l * kD, ln2_b + l * kD, ln1_g + l * kD, ln1_b + l * kD,
        stl, nullptr, nullptr, QKV + 256, 768);
    if (l == 0) {
      ffn_fused<0><<<kM / 64, 512, 0, stream>>>(
          QKV + 256, 768, c1w_bf, c1_b, c2w_bf, c2_b, log_seqs,
          nullptr, nullptr, stats + kM, nullptr, nullptr, nullptr, nullptr,
          X, 256);
    } else {
      ffn_fused<1><<<kM / 64, 512, 0, stream>>>(
          QKV + 256, 768, c1w_bf + 65536, c1_b + 256, c2w_bf + 65536, c2_b + 256,
          log_seqs, last_g, last_b, nullptr, item_emb, pos_seqs, neg_seqs, out,
          nullptr, 0);
    }
  }
}